// Round 7
// baseline (653.385 us; speedup 1.0000x reference)
//
#include <hip/hip_runtime.h>
#include <hip/hip_bf16.h>
#include <stdint.h>

typedef unsigned short u16;
typedef __bf16 bf16x8 __attribute__((ext_vector_type(8)));
typedef __attribute__((ext_vector_type(4))) float f32x4;
typedef __attribute__((ext_vector_type(16))) float f32x16;
typedef __attribute__((ext_vector_type(4))) unsigned short u16x4;
typedef __attribute__((ext_vector_type(4))) int i32x4;
typedef __attribute__((ext_vector_type(2))) unsigned u32x2;
typedef __attribute__((ext_vector_type(4))) unsigned u32x4;

#define T_ 2048

__device__ __forceinline__ u16 f2bf(float f) {
  __hip_bfloat16 h = __float2bfloat16(f);
  return __builtin_bit_cast(u16, h);
}
__device__ __forceinline__ float bf2f(u16 u) {
  __hip_bfloat16 h = __builtin_bit_cast(__hip_bfloat16, u);
  return __bfloat162float(h);
}
__device__ __forceinline__ unsigned pk2(float a, float b) {
  return (unsigned)f2bf(a) | ((unsigned)f2bf(b) << 16);
}
__device__ __forceinline__ void gload16(const u16* g, u16* l) {
  __builtin_amdgcn_global_load_lds((const __attribute__((address_space(1))) void*)g,
                                   (__attribute__((address_space(3))) void*)l, 16, 0, 0);
}

// ---------------- casts ----------------
__global__ __launch_bounds__(256) void cast_f32_bf16(const float* __restrict__ in,
                                                     u16* __restrict__ outp, int n) {
  int i = (blockIdx.x * 256 + threadIdx.x) * 4;
  if (i < n) {
    f32x4 v = *(const f32x4*)(in + i);
    u16x4 o;
    o.x = f2bf(v.x); o.y = f2bf(v.y); o.z = f2bf(v.z); o.w = f2bf(v.w);
    *(u16x4*)(outp + i) = o;
  }
}

// All six weight transposes in ONE dispatch (segment table) -> one ramp/tail.
struct CTSegs {
  const float* in[6];
  u16* out[6];
  int R[6], C[6], gx[6], start[6];
};
__global__ __launch_bounds__(256) void castT_multi(CTSegs S) {
  __shared__ float tile[32][33];
  int bid = blockIdx.x;
  int s = 0;
#pragma unroll
  for (int k = 1; k < 6; k++)
    if (bid >= S.start[k]) s = k;
  const float* in = S.in[s];
  u16* outp = S.out[s];
  const int R = S.R[s], C = S.C[s], gx = S.gx[s];
  const int local = bid - S.start[s];
  const int by = local / gx, bx = local - by * gx;
  int tx = threadIdx.x & 31, ty = threadIdx.x >> 5;
  int r0 = by * 32, c0 = bx * 32;
#pragma unroll
  for (int p = 0; p < 4; p++) {
    int rr = r0 + ty + p * 8;
    int cc = c0 + tx;
    tile[ty + p * 8][tx] = (cc < C) ? in[(size_t)rr * C + cc] : 0.f;
  }
  __syncthreads();
#pragma unroll
  for (int p = 0; p < 4; p++) {
    outp[(size_t)(c0 + ty + p * 8) * R + r0 + tx] = f2bf(tile[tx][ty + p * 8]);
  }
}

// ---------------- rmsnorm over rows (both norms, one dispatch) -------------
__device__ __forceinline__ void rms_body(const u16* __restrict__ in,
                                         u16* __restrict__ outp,
                                         const float* __restrict__ w,
                                         int D, int sin, int sout, int r) {
  int tid = threadIdx.x;
  int wave = tid >> 6, lane = tid & 63;
  __shared__ float sred[4];
  float vals[6];
  int E = D >> 8;
  float ss = 0.f;
  for (int e = 0; e < E; e++) {
    float v = bf2f(in[(size_t)r * sin + e * 256 + tid]);
    vals[e] = v;
    ss += v * v;
  }
#pragma unroll
  for (int d = 1; d < 64; d <<= 1) ss += __shfl_xor(ss, d, 64);
  if (lane == 0) sred[wave] = ss;
  __syncthreads();
  ss = sred[0] + sred[1] + sred[2] + sred[3];
  float rr = rsqrtf(ss / (float)D + 1e-6f);
  for (int e = 0; e < E; e++)
    outp[(size_t)r * sout + e * 256 + tid] = f2bf(vals[e] * rr * w[e * 256 + tid]);
}

__global__ __launch_bounds__(256) void rmsnorm_dual(const u16* __restrict__ cqkv,
                                                    u16* __restrict__ cq,
                                                    const float* __restrict__ qnw,
                                                    u16* __restrict__ ckv,
                                                    const float* __restrict__ kvnw) {
  int bid = blockIdx.x;
  if (bid < 4096)
    rms_body(cqkv, cq, qnw, 1536, 2176, 1536, bid);
  else
    rms_body(cqkv + 1536, ckv, kvnw, 512, 2176, 512, bid - 4096);
}

// ---------------- GEMM core (m97-structure, gload_lds staging) ------------
__device__ __forceinline__ void gemm_body(const u16* __restrict__ A,
                                          const u16* __restrict__ Bt,
                                          void* __restrict__ Cv,
                                          int M, int N, int K, int cf32,
                                          int m0, int n0, u16* As, u16* Bs) {
  const int tid = threadIdx.x;
  const int wave = tid >> 6, lane = tid & 63;
  const int wm = (wave >> 1) * 64, wn = (wave & 1) * 64;
  const int fr = lane & 15, fq = lane >> 4;
  f32x4 acc[4][4] = {};

  const int grow = 32 * wave + (lane >> 3);
  const int gchunk = (lane & 7) ^ (lane >> 3);
  const u16* ag = A + (size_t)(m0 + grow) * K + gchunk * 8;
  const u16* bg = Bt + (size_t)(n0 + grow) * K + gchunk * 8;
  u16* al = As + wave * 2048;
  u16* bl = Bs + wave * 2048;

  const u16* ard[2][4];
  const u16* brd[2][4];
#pragma unroll
  for (int ks = 0; ks < 2; ks++)
#pragma unroll
    for (int i = 0; i < 4; i++) {
      int ra = wm + 16 * i + fr;
      ard[ks][i] = As + ra * 64 + (((fq + ks * 4) ^ (ra & 7)) << 3);
      int rb = wn + 16 * i + fr;
      brd[ks][i] = Bs + rb * 64 + (((fq + ks * 4) ^ (rb & 7)) << 3);
    }

  for (int k0 = 0; k0 < K; k0 += 64) {
    if (k0) __syncthreads();
#pragma unroll
    for (int i = 0; i < 4; i++) {
      gload16(ag + k0 + (size_t)i * 8 * K, al + i * 512);
      gload16(bg + k0 + (size_t)i * 8 * K, bl + i * 512);
    }
    __syncthreads();
#pragma unroll
    for (int ks = 0; ks < 2; ks++) {
      bf16x8 af[4], bf[4];
#pragma unroll
      for (int i = 0; i < 4; i++) {
        af[i] = *(const bf16x8*)ard[ks][i];
        bf[i] = *(const bf16x8*)brd[ks][i];
      }
#pragma unroll
      for (int i = 0; i < 4; i++)
#pragma unroll
        for (int j = 0; j < 4; j++)
          acc[i][j] = __builtin_amdgcn_mfma_f32_16x16x32_bf16(af[i], bf[j], acc[i][j], 0, 0, 0);
    }
  }
  if (cf32) {
    float* C = (float*)Cv;
#pragma unroll
    for (int i = 0; i < 4; i++)
#pragma unroll
      for (int j = 0; j < 4; j++)
#pragma unroll
        for (int r = 0; r < 4; r++)
          C[(size_t)(m0 + wm + 16 * i + fq * 4 + r) * N + n0 + wn + 16 * j + fr] = acc[i][j][r];
  } else {
    u16* C = (u16*)Cv;
#pragma unroll
    for (int i = 0; i < 4; i++)
#pragma unroll
      for (int j = 0; j < 4; j++)
#pragma unroll
        for (int r = 0; r < 4; r++)
          C[(size_t)(m0 + wm + 16 * i + fq * 4 + r) * N + n0 + wn + 16 * j + fr] = f2bf(acc[i][j][r]);
  }
}

__global__ __launch_bounds__(256) void gemm_bt(const u16* __restrict__ A,
                                               const u16* __restrict__ Bt,
                                               void* __restrict__ Cv,
                                               int M, int N, int K, int cf32) {
  __shared__ u16 As[128 * 64];
  __shared__ u16 Bs[128 * 64];
  gemm_body(A, Bt, Cv, M, N, K, cf32, blockIdx.y * 128, blockIdx.x * 128, As, Bs);
}

// Two independent GEMMs fused into one dispatch: blockIdx.z selects params.
__global__ __launch_bounds__(256) void gemm_bt2(const u16* __restrict__ A0,
                                                const u16* __restrict__ B0,
                                                void* __restrict__ C0,
                                                int N0, int K0, int gx0,
                                                const u16* __restrict__ A1,
                                                const u16* __restrict__ B1,
                                                void* __restrict__ C1,
                                                int N1, int K1, int gx1) {
  __shared__ u16 As[128 * 64];
  __shared__ u16 Bs[128 * 64];
  if (blockIdx.z == 0) {
    if ((int)blockIdx.x >= gx0) return;
    gemm_body(A0, B0, C0, 4096, N0, K0, 0, blockIdx.y * 128, blockIdx.x * 128, As, Bs);
  } else {
    if ((int)blockIdx.x >= gx1) return;
    gemm_body(A1, B1, C1, 4096, N1, K1, 0, blockIdx.y * 128, blockIdx.x * 128, As, Bs);
  }
}

// ------------- q pack + kv pack fused into one dispatch --------------------
__global__ __launch_bounds__(256) void pack_dual(const u16* __restrict__ qnr,
                                                 const float* __restrict__ qhw,
                                                 const float* __restrict__ fcos,
                                                 const float* __restrict__ fsin,
                                                 u16* __restrict__ qp,
                                                 const u16* __restrict__ kvu,
                                                 const u16* __restrict__ kvr,
                                                 const float* __restrict__ khw,
                                                 u16* __restrict__ kp,
                                                 u16* __restrict__ vp) {
  __shared__ u16 vsl[128 * 66];
  int bid = blockIdx.x;
  if (bid < 16384) {
    // ---- qpack: head rmsnorm + rope + 1/sqrt(192) scale ----
    int gw = bid * 4 + (threadIdx.x >> 6);
    int lane = threadIdx.x & 63;
    int r = gw >> 4, h = gw & 15;
    int b = r >> 11, t = r & 2047;
    const float sc = 0.07216878364870323f;  // 1/sqrt(192), folded into Q
    float v0 = bf2f(qnr[(size_t)r * 3072 + h * 128 + lane]);
    float v1 = bf2f(qnr[(size_t)r * 3072 + h * 128 + 64 + lane]);
    float ss = v0 * v0 + v1 * v1;
#pragma unroll
    for (int d = 1; d < 64; d <<= 1) ss += __shfl_xor(ss, d, 64);
    float rr = rsqrtf(ss * (1.f / 128.f) + 1e-6f) * sc;
    size_t ob = ((size_t)(b * 16 + h) * 2048 + t) * 192;
    qp[ob + lane] = f2bf(v0 * rr * qhw[lane]);
    qp[ob + 64 + lane] = f2bf(v1 * rr * qhw[64 + lane]);
    if (lane < 32) {
      float a = bf2f(qnr[(size_t)r * 3072 + 2048 + h * 64 + 2 * lane]);
      float bb = bf2f(qnr[(size_t)r * 3072 + 2048 + h * 64 + 2 * lane + 1]);
      float c = fcos[t * 32 + lane], s = fsin[t * 32 + lane];
      qp[ob + 128 + 2 * lane] = f2bf((a * c - bb * s) * sc);
      qp[ob + 129 + 2 * lane] = f2bf((a * s + bb * c) * sc);
    }
  } else {
    // ---- kvpack ----
    int q = bid - 16384;
    int h = q & 15, tile = q >> 4;
    int r0 = tile * 64;
    int b = r0 >> 11;
    int tl = tile & 31;
    int tid = threadIdx.x, wave = tid >> 6, lane = tid & 63;
    int bh = b * 16 + h;
    for (int ii = 0; ii < 16; ii++) {
      int i = wave * 16 + ii;
      int r = r0 + i;
      int t = r & 2047;
      size_t kbase = (size_t)r * 4096 + h * 256;
      float v0 = bf2f(kvu[kbase + lane]);
      float v1 = bf2f(kvu[kbase + 64 + lane]);
      float ss = v0 * v0 + v1 * v1;
#pragma unroll
      for (int d = 1; d < 64; d <<= 1) ss += __shfl_xor(ss, d, 64);
      float rr = rsqrtf(ss * (1.f / 128.f) + 1e-6f);
      size_t ob = ((size_t)bh * 2048 + t) * 192;
      kp[ob + lane] = f2bf(v0 * rr * khw[lane]);
      kp[ob + 64 + lane] = f2bf(v1 * rr * khw[64 + lane]);
      vsl[lane * 66 + i] = kvu[kbase + 128 + lane];
      vsl[(lane + 64) * 66 + i] = kvu[kbase + 192 + lane];
      if (lane < 32) {
        float a = bf2f(kvr[(size_t)r * 2176 + 512 + 2 * lane]);
        float bb = bf2f(kvr[(size_t)r * 2176 + 512 + 2 * lane + 1]);
        float c = fcos[t * 32 + lane], s = fsin[t * 32 + lane];
        kp[ob + 128 + 2 * lane] = f2bf(a * c - bb * s);
        kp[ob + 129 + 2 * lane] = f2bf(a * s + bb * c);
      }
    }
    __syncthreads();
    u16* vb = vp + ((size_t)bh * 32 + tl) * 8192;  // [128 v][64 t] tile
    for (int u = 0; u < 32; u++) {
      int e = u * 256 + tid;
      vb[e] = vsl[(e >> 6) * 66 + (e & 63)];
    }
  }
}

// ---------------- flash attention (causal), S^T formulation ----------------
// No LDS staging: K/V fragments are read DIRECTLY from global (K+V per tile
// = 40KB, entire K/V stream is L2/L3-resident: FETCH_SIZE shows 33MB total).
// Every wave is fully independent -> 64-thread blocks, grid 2048 (64 row-
// waves x 32 bh), LPT order (heavy rw first). bid%8 = bh%8 keeps all blocks
// sharing a bh on one XCD's L2. P->PV B-fragment via permlane32_swap (T12).
__global__ __launch_bounds__(64, 4) void attn_kernel(const u16* __restrict__ Q,
                                                     const u16* __restrict__ Kp,
                                                     const u16* __restrict__ Vt,
                                                     u16* __restrict__ O) {
  const int lane = threadIdx.x;
  const int bid = blockIdx.x;
  const int rw = 63 - (bid >> 5);  // row-wave 0..63, heavy first
  const int bh = bid & 31;
  const int l31 = lane & 31, half = lane >> 5;
  const int b = bh >> 4, h = bh & 15;

  const char* kgb = (const char*)(Kp + (size_t)bh * T_ * 192);
  const char* vgb = (const char*)(Vt + (size_t)bh * 32 * 8192);

  const int qw0 = rw * 32;
  const int qg = qw0 + l31;
  const int jmax = rw >> 1;

  bf16x8 qf[12];
  {
    const u16* qbp = Q + ((size_t)bh * T_ + qg) * 192 + half * 8;
#pragma unroll
    for (int t = 0; t < 12; t++) qf[t] = *(const bf16x8*)(qbp + t * 16);
  }
  f32x16 oacc[4] = {};
  float m_i = -3.0e38f, l_i = 0.f;

  for (int j = 0; j <= jmax; j++) {
    const char* kg = kgb + (size_t)j * 24576;
    const char* vg = vgb + (size_t)j * 16384;

    f32x16 sa[2] = {};
    __builtin_amdgcn_s_setprio(1);
#pragma unroll
    for (int t = 0; t < 12; t++) {
      bf16x8 a0 = *(const bf16x8*)(kg + (size_t)l31 * 384 + (2 * t + half) * 16);
      bf16x8 a1 = *(const bf16x8*)(kg + (size_t)(32 + l31) * 384 + (2 * t + half) * 16);
      sa[0] = __builtin_amdgcn_mfma_f32_32x32x16_bf16(a0, qf[t], sa[0], 0, 0, 0);
      sa[1] = __builtin_amdgcn_mfma_f32_32x32x16_bf16(a1, qf[t], sa[1], 0, 0, 0);
    }
    __builtin_amdgcn_s_setprio(0);
    if (j * 64 + 63 > qw0) {
      int kb = j * 64 + 4 * half;
#pragma unroll
      for (int tt = 0; tt < 2; tt++)
#pragma unroll
        for (int r = 0; r < 16; r++) {
          int kk = kb + tt * 32 + (r & 3) + 8 * (r >> 2);
          if (kk > qg) sa[tt][r] = -3.0e38f;
        }
    }
    float mx = -3.0e38f;
#pragma unroll
    for (int r = 0; r < 16; r++) mx = fmaxf(mx, fmaxf(sa[0][r], sa[1][r]));
    mx = fmaxf(mx, __shfl_xor(mx, 32, 64));
    // defer-max: only rescale O when the running max actually grew (>8)
    if (!__all(mx <= m_i + 8.0f)) {
      float mn = fmaxf(m_i, mx);
      float al = exp2f((m_i - mn) * 1.44269504f);
      l_i *= al;
#pragma unroll
      for (int vt = 0; vt < 4; vt++)
#pragma unroll
        for (int r = 0; r < 16; r++) oacc[vt][r] *= al;
      m_i = mn;
    }
    float rs = 0.f;
#pragma unroll
    for (int tt = 0; tt < 2; tt++)
#pragma unroll
      for (int r = 0; r < 16; r++) {
        float p = exp2f((sa[tt][r] - m_i) * 1.44269504f);
        sa[tt][r] = p;
        rs += p;
      }
    rs += __shfl_xor(rs, 32, 64);
    l_i += rs;

    // ---- in-register P -> PV B-fragment via permlane32_swap (T12) ----
    bf16x8 pf[4];
#pragma unroll
    for (int tt = 0; tt < 2; tt++)
#pragma unroll
      for (int s = 0; s < 2; s++) {
        unsigned X0 = pk2(sa[tt][8 * s + 0], sa[tt][8 * s + 1]);
        unsigned X1 = pk2(sa[tt][8 * s + 2], sa[tt][8 * s + 3]);
        unsigned Y0 = pk2(sa[tt][8 * s + 4], sa[tt][8 * s + 5]);
        unsigned Y1 = pk2(sa[tt][8 * s + 6], sa[tt][8 * s + 7]);
        u32x2 r0 = __builtin_amdgcn_permlane32_swap(X0, Y0, false, false);
        u32x2 r1 = __builtin_amdgcn_permlane32_swap(X1, Y1, false, false);
        u32x4 w;
        w.x = r0.x;
        w.y = r1.x;
        w.z = r0.y;
        w.w = r1.y;
        pf[2 * tt + s] = __builtin_bit_cast(bf16x8, w);
      }

    __builtin_amdgcn_s_setprio(1);
#pragma unroll
    for (int t = 0; t < 4; t++) {
#pragma unroll
      for (int vt = 0; vt < 4; vt++) {
        bf16x8 vf = *(const bf16x8*)(vg + (size_t)(vt * 32 + l31) * 128 + (2 * t + half) * 16);
        oacc[vt] = __builtin_amdgcn_mfma_f32_32x32x16_bf16(vf, pf[t], oacc[vt], 0, 0, 0);
      }
    }
    __builtin_amdgcn_s_setprio(0);
  }
  float inv = 1.f / l_i;
  u16* orow = O + ((size_t)(b * T_ + qg)) * 2048 + h * 128 + 4 * half;
#pragma unroll
  for (int vt = 0; vt < 4; vt++)
#pragma unroll
    for (int qd = 0; qd < 4; qd++) {
      uint2 pk;
      pk.x = pk2(oacc[vt][qd * 4 + 0] * inv, oacc[vt][qd * 4 + 1] * inv);
      pk.y = pk2(oacc[vt][qd * 4 + 2] * inv, oacc[vt][qd * 4 + 3] * inv);
      *(uint2*)(orow + vt * 32 + qd * 8) = pk;
    }
}

extern "C" void kernel_launch(void* const* d_in, const int* in_sizes, int n_in,
                              void* d_out, int out_size, void* d_ws, size_t ws_size,
                              hipStream_t stream) {
  const float* x    = (const float*)d_in[0];
  const float* fcos = (const float*)d_in[1];
  const float* fsin = (const float*)d_in[2];
  const float* wqd  = (const float*)d_in[3];
  const float* qnw  = (const float*)d_in[4];
  const float* wqun = (const float*)d_in[5];
  const float* wqur = (const float*)d_in[6];
  const float* wkvd = (const float*)d_in[7];
  const float* kvnw = (const float*)d_in[8];
  const float* wkvu = (const float*)d_in[9];
  const float* qhnw = (const float*)d_in[10];
  const float* khnw = (const float*)d_in[11];
  const float* wwo  = (const float*)d_in[12];
  float* out = (float*)d_out;
  char* ws = (char*)d_ws;

  size_t off = 0;
  auto alloc = [&](size_t elems) -> u16* {
    u16* p = (u16*)(ws + off);
    off += ((elems * 2 + 255) & ~(size_t)255);
    return p;
  };
  u16* x16   = alloc(4096ull * 2048);
  u16* bqkvd = alloc(2176ull * 2048);  // fused q_down(1536) + kv_down(640)
  u16* bqu   = alloc(3072ull * 1536);  // merged q_up
  u16* bkvu  = alloc(4096ull * 512);
  u16* bwo   = alloc(2048ull * 2048);
  u16* cqkv  = alloc(4096ull * 2176);  // fused down-proj output
  u16* cq    = alloc(4096ull * 1536);
  u16* qnr   = alloc(4096ull * 3072);
  u16* ckv   = alloc(4096ull * 512);
  u16* kvu   = alloc(4096ull * 4096);
  u16* qp    = alloc(32ull * 2048 * 192);
  u16* kp    = alloc(32ull * 2048 * 192);
  u16* vp    = alloc(32ull * 2048 * 128);
  u16* ao    = alloc(4096ull * 2048);
  if (ws_size < off) return;

  cast_f32_bf16<<<8192, 256, 0, stream>>>(x, x16, 4096 * 2048);

  // six weight transposes, one dispatch
  CTSegs S;
  S.in[0] = wqd;  S.out[0] = bqkvd;                 S.R[0] = 2048; S.C[0] = 1536; S.gx[0] = 48;
  S.in[1] = wkvd; S.out[1] = bqkvd + 1536ull * 2048; S.R[1] = 2048; S.C[1] = 576;  S.gx[1] = 20;
  S.in[2] = wqun; S.out[2] = bqu;                   S.R[2] = 1536; S.C[2] = 2048; S.gx[2] = 64;
  S.in[3] = wqur; S.out[3] = bqu + 2048ull * 1536;  S.R[3] = 1536; S.C[3] = 1024; S.gx[3] = 32;
  S.in[4] = wkvu; S.out[4] = bkvu;                  S.R[4] = 512;  S.C[4] = 4096; S.gx[4] = 128;
  S.in[5] = wwo;  S.out[5] = bwo;                   S.R[5] = 2048; S.C[5] = 2048; S.gx[5] = 64;
  int tot = 0;
  int gy[6] = {64, 64, 48, 48, 16, 64};
  for (int k = 0; k < 6; k++) { S.start[k] = tot; tot += S.gx[k] * gy[k]; }
  castT_multi<<<tot, 256, 0, stream>>>(S);

  gemm_bt<<<dim3(17, 32), 256, 0, stream>>>(x16, bqkvd, cqkv, 4096, 2176, 2048, 0);
  rmsnorm_dual<<<8192, 256, 0, stream>>>(cqkv, cq, qnw, ckv, kvnw);
  // q_up (K=1536) and kv_up (K=512) fused: long-K z=0 first, short-K backfills
  gemm_bt2<<<dim3(32, 32, 2), 256, 0, stream>>>(cq, bqu, qnr, 3072, 1536, 24,
                                                ckv, bkvu, kvu, 4096, 512, 32);
  pack_dual<<<17408, 256, 0, stream>>>(qnr, qhnw, fcos, fsin, qp,
                                       kvu, cqkv + 1536, khnw, kp, vp);
  attn_kernel<<<2048, 64, 0, stream>>>(qp, kp, vp, ao);
  gemm_bt<<<dim3(16, 32), 256, 0, stream>>>(ao, bwo, out, 4096, 2048, 2048, 1);
}

// Round 8
// 484.415 us; speedup vs baseline: 1.3488x; 1.3488x over previous
//
#include <hip/hip_runtime.h>
#include <hip/hip_bf16.h>
#include <stdint.h>

typedef unsigned short u16;
typedef __bf16 bf16x8 __attribute__((ext_vector_type(8)));
typedef __attribute__((ext_vector_type(4))) float f32x4;
typedef __attribute__((ext_vector_type(16))) float f32x16;
typedef __attribute__((ext_vector_type(4))) unsigned short u16x4;
typedef __attribute__((ext_vector_type(4))) int i32x4;
typedef __attribute__((ext_vector_type(2))) unsigned u32x2;
typedef __attribute__((ext_vector_type(4))) unsigned u32x4;

#define T_ 2048

__device__ __forceinline__ u16 f2bf(float f) {
  __hip_bfloat16 h = __float2bfloat16(f);
  return __builtin_bit_cast(u16, h);
}
__device__ __forceinline__ float bf2f(u16 u) {
  __hip_bfloat16 h = __builtin_bit_cast(__hip_bfloat16, u);
  return __bfloat162float(h);
}
__device__ __forceinline__ unsigned pk2(float a, float b) {
  return (unsigned)f2bf(a) | ((unsigned)f2bf(b) << 16);
}
__device__ __forceinline__ void gload16(const u16* g, u16* l) {
  __builtin_amdgcn_global_load_lds((const __attribute__((address_space(1))) void*)g,
                                   (__attribute__((address_space(3))) void*)l, 16, 0, 0);
}

// ---------------- casts ----------------
__global__ __launch_bounds__(256) void cast_f32_bf16(const float* __restrict__ in,
                                                     u16* __restrict__ outp, int n) {
  int i = (blockIdx.x * 256 + threadIdx.x) * 4;
  if (i < n) {
    f32x4 v = *(const f32x4*)(in + i);
    u16x4 o;
    o.x = f2bf(v.x); o.y = f2bf(v.y); o.z = f2bf(v.z); o.w = f2bf(v.w);
    *(u16x4*)(outp + i) = o;
  }
}

// All six weight transposes in ONE dispatch (segment table) -> one ramp/tail.
struct CTSegs {
  const float* in[6];
  u16* out[6];
  int R[6], C[6], gx[6], start[6];
};
__global__ __launch_bounds__(256) void castT_multi(CTSegs S) {
  __shared__ float tile[32][33];
  int bid = blockIdx.x;
  int s = 0;
#pragma unroll
  for (int k = 1; k < 6; k++)
    if (bid >= S.start[k]) s = k;
  const float* in = S.in[s];
  u16* outp = S.out[s];
  const int R = S.R[s], C = S.C[s], gx = S.gx[s];
  const int local = bid - S.start[s];
  const int by = local / gx, bx = local - by * gx;
  int tx = threadIdx.x & 31, ty = threadIdx.x >> 5;
  int r0 = by * 32, c0 = bx * 32;
#pragma unroll
  for (int p = 0; p < 4; p++) {
    int rr = r0 + ty + p * 8;
    int cc = c0 + tx;
    tile[ty + p * 8][tx] = (cc < C) ? in[(size_t)rr * C + cc] : 0.f;
  }
  __syncthreads();
#pragma unroll
  for (int p = 0; p < 4; p++) {
    outp[(size_t)(c0 + ty + p * 8) * R + r0 + tx] = f2bf(tile[tx][ty + p * 8]);
  }
}

// ---------------- rmsnorm over rows (both norms, one dispatch) -------------
__device__ __forceinline__ void rms_body(const u16* __restrict__ in,
                                         u16* __restrict__ outp,
                                         const float* __restrict__ w,
                                         int D, int sin, int sout, int r) {
  int tid = threadIdx.x;
  int wave = tid >> 6, lane = tid & 63;
  __shared__ float sred[4];
  float vals[6];
  int E = D >> 8;
  float ss = 0.f;
  for (int e = 0; e < E; e++) {
    float v = bf2f(in[(size_t)r * sin + e * 256 + tid]);
    vals[e] = v;
    ss += v * v;
  }
#pragma unroll
  for (int d = 1; d < 64; d <<= 1) ss += __shfl_xor(ss, d, 64);
  if (lane == 0) sred[wave] = ss;
  __syncthreads();
  ss = sred[0] + sred[1] + sred[2] + sred[3];
  float rr = rsqrtf(ss / (float)D + 1e-6f);
  for (int e = 0; e < E; e++)
    outp[(size_t)r * sout + e * 256 + tid] = f2bf(vals[e] * rr * w[e * 256 + tid]);
}

__global__ __launch_bounds__(256) void rmsnorm_dual(const u16* __restrict__ cqkv,
                                                    u16* __restrict__ cq,
                                                    const float* __restrict__ qnw,
                                                    u16* __restrict__ ckv,
                                                    const float* __restrict__ kvnw) {
  int bid = blockIdx.x;
  if (bid < 4096)
    rms_body(cqkv, cq, qnw, 1536, 2176, 1536, bid);
  else
    rms_body(cqkv + 1536, ckv, kvnw, 512, 2176, 512, bid - 4096);
}

// ---------------- GEMM core (m97-structure, gload_lds staging) ------------
// 32x32x16 MFMA variant: per wave 64x64 out = 2x2 of 32x32 tiles; per K=64
// tile 4 k-steps x 4 MFMA = 16 mfma_32x32x16 (129 cyc) vs 32 mfma_16x16x32
// (155 cyc) -- ~17% fewer matrix-pipe cycles, same LDS bytes (16 b128 reads).
// C/D mapping (m74/m101, HW-verified): col = lane&31,
// row = (reg&3) + 8*(reg>>2) + 4*(lane>>5).
__device__ __forceinline__ void gemm_body(const u16* __restrict__ A,
                                          const u16* __restrict__ Bt,
                                          void* __restrict__ Cv,
                                          int M, int N, int K, int cf32,
                                          int m0, int n0, u16* As, u16* Bs) {
  const int tid = threadIdx.x;
  const int wave = tid >> 6, lane = tid & 63;
  const int l31 = lane & 31, half = lane >> 5, xr = l31 & 7;
  const int wm = (wave >> 1) * 64, wn = (wave & 1) * 64;
  f32x16 acc[2][2] = {};

  const int grow = 32 * wave + (lane >> 3);
  const int gchunk = (lane & 7) ^ (lane >> 3);
  const u16* ag = A + (size_t)(m0 + grow) * K + gchunk * 8;
  const u16* bg = Bt + (size_t)(n0 + grow) * K + gchunk * 8;
  u16* al = As + wave * 2048;
  u16* bl = Bs + wave * 2048;

  // fragment row bases (swizzled: chunk c of row r lives at slot c^(r&7))
  const u16* arow[2] = {As + (wm + l31) * 64, As + (wm + 32 + l31) * 64};
  const u16* brow[2] = {Bs + (wn + l31) * 64, Bs + (wn + 32 + l31) * 64};

  for (int k0 = 0; k0 < K; k0 += 64) {
    if (k0) __syncthreads();
#pragma unroll
    for (int i = 0; i < 4; i++) {
      gload16(ag + k0 + (size_t)i * 8 * K, al + i * 512);
      gload16(bg + k0 + (size_t)i * 8 * K, bl + i * 512);
    }
    __syncthreads();
#pragma unroll
    for (int t = 0; t < 4; t++) {
      int sl = ((2 * t + half) ^ xr) << 3;
      bf16x8 af0 = *(const bf16x8*)(arow[0] + sl);
      bf16x8 af1 = *(const bf16x8*)(arow[1] + sl);
      bf16x8 bf0 = *(const bf16x8*)(brow[0] + sl);
      bf16x8 bf1 = *(const bf16x8*)(brow[1] + sl);
      acc[0][0] = __builtin_amdgcn_mfma_f32_32x32x16_bf16(af0, bf0, acc[0][0], 0, 0, 0);
      acc[0][1] = __builtin_amdgcn_mfma_f32_32x32x16_bf16(af0, bf1, acc[0][1], 0, 0, 0);
      acc[1][0] = __builtin_amdgcn_mfma_f32_32x32x16_bf16(af1, bf0, acc[1][0], 0, 0, 0);
      acc[1][1] = __builtin_amdgcn_mfma_f32_32x32x16_bf16(af1, bf1, acc[1][1], 0, 0, 0);
    }
  }
  if (cf32) {
    float* C = (float*)Cv;
#pragma unroll
    for (int mi = 0; mi < 2; mi++)
#pragma unroll
      for (int nj = 0; nj < 2; nj++)
#pragma unroll
        for (int r = 0; r < 16; r++) {
          int row = m0 + wm + 32 * mi + (r & 3) + 8 * (r >> 2) + 4 * half;
          C[(size_t)row * N + n0 + wn + 32 * nj + l31] = acc[mi][nj][r];
        }
  } else {
    u16* C = (u16*)Cv;
#pragma unroll
    for (int mi = 0; mi < 2; mi++)
#pragma unroll
      for (int nj = 0; nj < 2; nj++)
#pragma unroll
        for (int r = 0; r < 16; r++) {
          int row = m0 + wm + 32 * mi + (r & 3) + 8 * (r >> 2) + 4 * half;
          C[(size_t)row * N + n0 + wn + 32 * nj + l31] = f2bf(acc[mi][nj][r]);
        }
  }
}

__global__ __launch_bounds__(256) void gemm_bt(const u16* __restrict__ A,
                                               const u16* __restrict__ Bt,
                                               void* __restrict__ Cv,
                                               int M, int N, int K, int cf32) {
  __shared__ u16 As[128 * 64];
  __shared__ u16 Bs[128 * 64];
  gemm_body(A, Bt, Cv, M, N, K, cf32, blockIdx.y * 128, blockIdx.x * 128, As, Bs);
}

// Two independent GEMMs fused into one dispatch: blockIdx.z selects params.
__global__ __launch_bounds__(256) void gemm_bt2(const u16* __restrict__ A0,
                                                const u16* __restrict__ B0,
                                                void* __restrict__ C0,
                                                int N0, int K0, int gx0,
                                                const u16* __restrict__ A1,
                                                const u16* __restrict__ B1,
                                                void* __restrict__ C1,
                                                int N1, int K1, int gx1) {
  __shared__ u16 As[128 * 64];
  __shared__ u16 Bs[128 * 64];
  if (blockIdx.z == 0) {
    if ((int)blockIdx.x >= gx0) return;
    gemm_body(A0, B0, C0, 4096, N0, K0, 0, blockIdx.y * 128, blockIdx.x * 128, As, Bs);
  } else {
    if ((int)blockIdx.x >= gx1) return;
    gemm_body(A1, B1, C1, 4096, N1, K1, 0, blockIdx.y * 128, blockIdx.x * 128, As, Bs);
  }
}

// ------------- q pack + kv pack fused into one dispatch --------------------
__global__ __launch_bounds__(256) void pack_dual(const u16* __restrict__ qnr,
                                                 const float* __restrict__ qhw,
                                                 const float* __restrict__ fcos,
                                                 const float* __restrict__ fsin,
                                                 u16* __restrict__ qp,
                                                 const u16* __restrict__ kvu,
                                                 const u16* __restrict__ kvr,
                                                 const float* __restrict__ khw,
                                                 u16* __restrict__ kp,
                                                 u16* __restrict__ vp) {
  __shared__ u16 vsl[128 * 66];
  int bid = blockIdx.x;
  if (bid < 16384) {
    // ---- qpack: head rmsnorm + rope + 1/sqrt(192) scale ----
    int gw = bid * 4 + (threadIdx.x >> 6);
    int lane = threadIdx.x & 63;
    int r = gw >> 4, h = gw & 15;
    int b = r >> 11, t = r & 2047;
    const float sc = 0.07216878364870323f;  // 1/sqrt(192), folded into Q
    float v0 = bf2f(qnr[(size_t)r * 3072 + h * 128 + lane]);
    float v1 = bf2f(qnr[(size_t)r * 3072 + h * 128 + 64 + lane]);
    float ss = v0 * v0 + v1 * v1;
#pragma unroll
    for (int d = 1; d < 64; d <<= 1) ss += __shfl_xor(ss, d, 64);
    float rr = rsqrtf(ss * (1.f / 128.f) + 1e-6f) * sc;
    size_t ob = ((size_t)(b * 16 + h) * 2048 + t) * 192;
    qp[ob + lane] = f2bf(v0 * rr * qhw[lane]);
    qp[ob + 64 + lane] = f2bf(v1 * rr * qhw[64 + lane]);
    if (lane < 32) {
      float a = bf2f(qnr[(size_t)r * 3072 + 2048 + h * 64 + 2 * lane]);
      float bb = bf2f(qnr[(size_t)r * 3072 + 2048 + h * 64 + 2 * lane + 1]);
      float c = fcos[t * 32 + lane], s = fsin[t * 32 + lane];
      qp[ob + 128 + 2 * lane] = f2bf((a * c - bb * s) * sc);
      qp[ob + 129 + 2 * lane] = f2bf((a * s + bb * c) * sc);
    }
  } else {
    // ---- kvpack ----
    int q = bid - 16384;
    int h = q & 15, tile = q >> 4;
    int r0 = tile * 64;
    int b = r0 >> 11;
    int tl = tile & 31;
    int tid = threadIdx.x, wave = tid >> 6, lane = tid & 63;
    int bh = b * 16 + h;
    for (int ii = 0; ii < 16; ii++) {
      int i = wave * 16 + ii;
      int r = r0 + i;
      int t = r & 2047;
      size_t kbase = (size_t)r * 4096 + h * 256;
      float v0 = bf2f(kvu[kbase + lane]);
      float v1 = bf2f(kvu[kbase + 64 + lane]);
      float ss = v0 * v0 + v1 * v1;
#pragma unroll
      for (int d = 1; d < 64; d <<= 1) ss += __shfl_xor(ss, d, 64);
      float rr = rsqrtf(ss * (1.f / 128.f) + 1e-6f);
      size_t ob = ((size_t)bh * 2048 + t) * 192;
      kp[ob + lane] = f2bf(v0 * rr * khw[lane]);
      kp[ob + 64 + lane] = f2bf(v1 * rr * khw[64 + lane]);
      vsl[lane * 66 + i] = kvu[kbase + 128 + lane];
      vsl[(lane + 64) * 66 + i] = kvu[kbase + 192 + lane];
      if (lane < 32) {
        float a = bf2f(kvr[(size_t)r * 2176 + 512 + 2 * lane]);
        float bb = bf2f(kvr[(size_t)r * 2176 + 512 + 2 * lane + 1]);
        float c = fcos[t * 32 + lane], s = fsin[t * 32 + lane];
        kp[ob + 128 + 2 * lane] = f2bf(a * c - bb * s);
        kp[ob + 129 + 2 * lane] = f2bf(a * s + bb * c);
      }
    }
    __syncthreads();
    u16* vb = vp + ((size_t)bh * 32 + tl) * 8192;  // [128 v][64 t] tile
    for (int u = 0; u < 32; u++) {
      int e = u * 256 + tid;
      vb[e] = vsl[(e >> 6) * 66 + (e & 63)];
    }
  }
}

// ---------------- flash attention (causal), S^T formulation ----------------
// Round-6 measured best (91.1 us). 512 blocks, one q-block (128 rows) each;
// complementary pairing. LDS 48KB (K 32K + V 16K). P never touches LDS:
// PV B-fragment assembled in-register with v_permlane32_swap (T12).
__global__ __launch_bounds__(256, 2) void attn_kernel(const u16* __restrict__ Q,
                                                      const u16* __restrict__ Kp,
                                                      const u16* __restrict__ Vt,
                                                      u16* __restrict__ O) {
  __shared__ u16 Ks[64 * 256];
  __shared__ u16 Vs[128 * 64];
  const int tid = threadIdx.x;
  const int wave = tid >> 6, lane = tid & 63;
  const int n = blockIdx.x;
  const int qb = (n < 256) ? (15 - (n >> 5)) : ((n - 256) >> 5);
  const int bh = n & 31;
  const int l31 = lane & 31, half = lane >> 5, xr = lane & 7;
  const int b = bh >> 4, h = bh & 15;

  const char* kgb = (const char*)(Kp + (size_t)bh * T_ * 192);
  const char* vgb = (const char*)(Vt + (size_t)bh * 32 * 8192);
  u16* kw[6];
  u16* vw[4];
#pragma unroll
  for (int c = 0; c < 6; c++) {
    unsigned fo = c * 4096 + tid * 16;
    unsigned row = fo / 384u;
    unsigned chunk = (fo - row * 384) >> 4;
    kw[c] = Ks + row * 256 + ((chunk ^ (row & 7)) << 3);
  }
#pragma unroll
  for (int c = 0; c < 4; c++) {
    unsigned fo = c * 4096 + tid * 16;
    unsigned row = fo >> 7;
    unsigned chunk = (fo >> 4) & 7;
    vw[c] = Vs + row * 64 + ((chunk ^ (row & 7)) << 3);
  }
  const u16* krd0 = Ks + l31 * 256;
  const u16* krd1 = Ks + (32 + l31) * 256;
  const u16* vrd = Vs + l31 * 64;
  i32x4 kreg[6], vreg[4];

  const int qw0 = qb * 128 + wave * 32;
  const int qg = qw0 + l31;
  const int jmax = 2 * qb + 1;

  bf16x8 qf[12];
  {
    const u16* qbp = Q + ((size_t)bh * T_ + qg) * 192 + half * 8;
#pragma unroll
    for (int t = 0; t < 12; t++) qf[t] = *(const bf16x8*)(qbp + t * 16);
  }
  f32x16 oacc[4] = {};
  float m_i = -3.0e38f, l_i = 0.f;

#pragma unroll
  for (int c = 0; c < 6; c++) kreg[c] = *(const i32x4*)(kgb + c * 4096 + tid * 16);
#pragma unroll
  for (int c = 0; c < 4; c++) vreg[c] = *(const i32x4*)(vgb + c * 4096 + tid * 16);

  for (int j = 0; j <= jmax; j++) {
    if (j) __syncthreads();
#pragma unroll
    for (int c = 0; c < 6; c++) *(i32x4*)kw[c] = kreg[c];
#pragma unroll
    for (int c = 0; c < 4; c++) *(i32x4*)vw[c] = vreg[c];
    __syncthreads();
    if (j < jmax) {
      const char* kg = kgb + (size_t)(j + 1) * 24576;
      const char* vg = vgb + (size_t)(j + 1) * 16384;
#pragma unroll
      for (int c = 0; c < 6; c++) kreg[c] = *(const i32x4*)(kg + c * 4096 + tid * 16);
#pragma unroll
      for (int c = 0; c < 4; c++) vreg[c] = *(const i32x4*)(vg + c * 4096 + tid * 16);
    }
    if (j * 64 > qw0 + 31) continue;

    f32x16 sa[2] = {};
    __builtin_amdgcn_s_setprio(1);
#pragma unroll
    for (int t = 0; t < 12; t++) {
      int sl = ((2 * t + half) ^ xr) << 3;
      bf16x8 a0 = *(const bf16x8*)(krd0 + sl);
      bf16x8 a1 = *(const bf16x8*)(krd1 + sl);
      sa[0] = __builtin_amdgcn_mfma_f32_32x32x16_bf16(a0, qf[t], sa[0], 0, 0, 0);
      sa[1] = __builtin_amdgcn_mfma_f32_32x32x16_bf16(a1, qf[t], sa[1], 0, 0, 0);
    }
    __builtin_amdgcn_s_setprio(0);
    if (j * 64 + 63 > qw0) {
      int kb = j * 64 + 4 * half;
#pragma unroll
      for (int tt = 0; tt < 2; tt++)
#pragma unroll
        for (int r = 0; r < 16; r++) {
          int kk = kb + tt * 32 + (r & 3) + 8 * (r >> 2);
          if (kk > qg) sa[tt][r] = -3.0e38f;
        }
    }
    float mx = -3.0e38f;
#pragma unroll
    for (int r = 0; r < 16; r++) mx = fmaxf(mx, fmaxf(sa[0][r], sa[1][r]));
    mx = fmaxf(mx, __shfl_xor(mx, 32, 64));
    // defer-max: only rescale O when the running max actually grew (>8)
    if (!__all(mx <= m_i + 8.0f)) {
      float mn = fmaxf(m_i, mx);
      float al = exp2f((m_i - mn) * 1.44269504f);
      l_i *= al;
#pragma unroll
      for (int vt = 0; vt < 4; vt++)
#pragma unroll
        for (int r = 0; r < 16; r++) oacc[vt][r] *= al;
      m_i = mn;
    }
    float rs = 0.f;
#pragma unroll
    for (int tt = 0; tt < 2; tt++)
#pragma unroll
      for (int r = 0; r < 16; r++) {
        float p = exp2f((sa[tt][r] - m_i) * 1.44269504f);
        sa[tt][r] = p;
        rs += p;
      }
    rs += __shfl_xor(rs, 32, 64);
    l_i += rs;

    // ---- in-register P -> PV B-fragment via permlane32_swap (T12) ----
    bf16x8 pf[4];
#pragma unroll
    for (int tt = 0; tt < 2; tt++)
#pragma unroll
      for (int s = 0; s < 2; s++) {
        unsigned X0 = pk2(sa[tt][8 * s + 0], sa[tt][8 * s + 1]);
        unsigned X1 = pk2(sa[tt][8 * s + 2], sa[tt][8 * s + 3]);
        unsigned Y0 = pk2(sa[tt][8 * s + 4], sa[tt][8 * s + 5]);
        unsigned Y1 = pk2(sa[tt][8 * s + 6], sa[tt][8 * s + 7]);
        u32x2 r0 = __builtin_amdgcn_permlane32_swap(X0, Y0, false, false);
        u32x2 r1 = __builtin_amdgcn_permlane32_swap(X1, Y1, false, false);
        u32x4 w;
        w.x = r0.x;
        w.y = r1.x;
        w.z = r0.y;
        w.w = r1.y;
        pf[2 * tt + s] = __builtin_bit_cast(bf16x8, w);
      }

    __builtin_amdgcn_s_setprio(1);
#pragma unroll
    for (int t = 0; t < 4; t++) {
#pragma unroll
      for (int vt = 0; vt < 4; vt++) {
        bf16x8 vf = *(const bf16x8*)(vrd + vt * 32 * 64 + (((2 * t + half) ^ xr) << 3));
        oacc[vt] = __builtin_amdgcn_mfma_f32_32x32x16_bf16(vf, pf[t], oacc[vt], 0, 0, 0);
      }
    }
    __builtin_amdgcn_s_setprio(0);
  }
  float inv = 1.f / l_i;
  u16* orow = O + ((size_t)(b * T_ + qg)) * 2048 + h * 128 + 4 * half;
#pragma unroll
  for (int vt = 0; vt < 4; vt++)
#pragma unroll
    for (int qd = 0; qd < 4; qd++) {
      uint2 pk;
      pk.x = pk2(oacc[vt][qd * 4 + 0] * inv, oacc[vt][qd * 4 + 1] * inv);
      pk.y = pk2(oacc[vt][qd * 4 + 2] * inv, oacc[vt][qd * 4 + 3] * inv);
      *(uint2*)(orow + vt * 32 + qd * 8) = pk;
    }
}

extern "C" void kernel_launch(void* const* d_in, const int* in_sizes, int n_in,
                              void* d_out, int out_size, void* d_ws, size_t ws_size,
                              hipStream_t stream) {
  const float* x    = (const float*)d_in[0];
  const float* fcos = (const float*)d_in[1];
  const float* fsin = (const float*)d_in[2];
  const float* wqd  = (const float*)d_in[3];
  const float* qnw  = (const float*)d_in[4];
  const float* wqun = (const float*)d_in[5];
  const float* wqur = (const float*)d_in[6];
  const float* wkvd = (const float*)d_in[7];
  const float* kvnw = (const float*)d_in[8];
  const float* wkvu = (const float*)d_in[9];
  const float* qhnw = (const float*)d_in[10];
  const float* khnw = (const float*)d_in[11];
  const float* wwo  = (const float*)d_in[12];
  float* out = (float*)d_out;
  char* ws = (char*)d_ws;

  size_t off = 0;
  auto alloc = [&](size_t elems) -> u16* {
    u16* p = (u16*)(ws + off);
    off += ((elems * 2 + 255) & ~(size_t)255);
    return p;
  };
  u16* x16   = alloc(4096ull * 2048);
  u16* bqkvd = alloc(2176ull * 2048);  // fused q_down(1536) + kv_down(640)
  u16* bqu   = alloc(3072ull * 1536);  // merged q_up
  u16* bkvu  = alloc(4096ull * 512);
  u16* bwo   = alloc(2048ull * 2048);
  u16* cqkv  = alloc(4096ull * 2176);  // fused down-proj output
  u16* cq    = alloc(4096ull * 1536);
  u16* qnr   = alloc(4096ull * 3072);
  u16* ckv   = alloc(4096ull * 512);
  u16* kvu   = alloc(4096ull * 4096);
  u16* qp    = alloc(32ull * 2048 * 192);
  u16* kp    = alloc(32ull * 2048 * 192);
  u16* vp    = alloc(32ull * 2048 * 128);
  u16* ao    = alloc(4096ull * 2048);
  if (ws_size < off) return;

  cast_f32_bf16<<<8192, 256, 0, stream>>>(x, x16, 4096 * 2048);

  // six weight transposes, one dispatch
  CTSegs S;
  S.in[0] = wqd;  S.out[0] = bqkvd;                 S.R[0] = 2048; S.C[0] = 1536; S.gx[0] = 48;
  S.in[1] = wkvd; S.out[1] = bqkvd + 1536ull * 2048; S.R[1] = 2048; S.C[1] = 576;  S.gx[1] = 20;
  S.in[2] = wqun; S.out[2] = bqu;                   S.R[2] = 1536; S.C[2] = 2048; S.gx[2] = 64;
  S.in[3] = wqur; S.out[3] = bqu + 2048ull * 1536;  S.R[3] = 1536; S.C[3] = 1024; S.gx[3] = 32;
  S.in[4] = wkvu; S.out[4] = bkvu;                  S.R[4] = 512;  S.C[4] = 4096; S.gx[4] = 128;
  S.in[5] = wwo;  S.out[5] = bwo;                   S.R[5] = 2048; S.C[5] = 2048; S.gx[5] = 64;
  int tot = 0;
  int gy[6] = {64, 64, 48, 48, 16, 64};
  for (int k = 0; k < 6; k++) { S.start[k] = tot; tot += S.gx[k] * gy[k]; }
  castT_multi<<<tot, 256, 0, stream>>>(S);

  gemm_bt<<<dim3(17, 32), 256, 0, stream>>>(x16, bqkvd, cqkv, 4096, 2176, 2048, 0);
  rmsnorm_dual<<<8192, 256, 0, stream>>>(cqkv, cq, qnw, ckv, kvnw);
  // q_up (K=1536) and kv_up (K=512) fused: long-K z=0 first, short-K backfills
  gemm_bt2<<<dim3(32, 32, 2), 256, 0, stream>>>(cq, bqu, qnr, 3072, 1536, 24,
                                                ckv, bkvu, kvu, 4096, 512, 32);
  pack_dual<<<17408, 256, 0, stream>>>(qnr, qhnw, fcos, fsin, qp,
                                       kvu, cqkv + 1536, khnw, kp, vp);
  attn_kernel<<<512, 256, 0, stream>>>(qp, kp, vp, ao);
  gemm_bt<<<dim3(16, 32), 256, 0, stream>>>(ao, bwo, out, 4096, 2048, 2048, 1);
}

// Round 9
// 451.493 us; speedup vs baseline: 1.4472x; 1.0729x over previous
//
#include <hip/hip_runtime.h>
#include <hip/hip_bf16.h>
#include <stdint.h>

typedef unsigned short u16;
typedef __bf16 bf16x8 __attribute__((ext_vector_type(8)));
typedef __attribute__((ext_vector_type(2))) float f32x2;
typedef __attribute__((ext_vector_type(4))) float f32x4;
typedef __attribute__((ext_vector_type(16))) float f32x16;
typedef __attribute__((ext_vector_type(4))) unsigned short u16x4;
typedef __attribute__((ext_vector_type(4))) int i32x4;
typedef __attribute__((ext_vector_type(2))) unsigned u32x2;
typedef __attribute__((ext_vector_type(4))) unsigned u32x4;

#define T_ 2048

__device__ __forceinline__ u16 f2bf(float f) {
  __hip_bfloat16 h = __float2bfloat16(f);
  return __builtin_bit_cast(u16, h);
}
__device__ __forceinline__ float bf2f(u16 u) {
  __hip_bfloat16 h = __builtin_bit_cast(__hip_bfloat16, u);
  return __bfloat162float(h);
}
__device__ __forceinline__ unsigned pk2(float a, float b) {
  return (unsigned)f2bf(a) | ((unsigned)f2bf(b) << 16);
}
__device__ __forceinline__ void gload16(const u16* g, u16* l) {
  __builtin_amdgcn_global_load_lds((const __attribute__((address_space(1))) void*)g,
                                   (__attribute__((address_space(3))) void*)l, 16, 0, 0);
}

// ---------------- casts ----------------
__global__ __launch_bounds__(256) void cast_f32_bf16(const float* __restrict__ in,
                                                     u16* __restrict__ outp, int n) {
  int i = (blockIdx.x * 256 + threadIdx.x) * 4;
  if (i < n) {
    f32x4 v = *(const f32x4*)(in + i);
    u16x4 o;
    o.x = f2bf(v.x); o.y = f2bf(v.y); o.z = f2bf(v.z); o.w = f2bf(v.w);
    *(u16x4*)(outp + i) = o;
  }
}

// All six weight transposes in ONE dispatch (segment table) -> one ramp/tail.
struct CTSegs {
  const float* in[6];
  u16* out[6];
  int R[6], C[6], gx[6], start[6];
};
__global__ __launch_bounds__(256) void castT_multi(CTSegs S) {
  __shared__ float tile[32][33];
  int bid = blockIdx.x;
  int s = 0;
#pragma unroll
  for (int k = 1; k < 6; k++)
    if (bid >= S.start[k]) s = k;
  const float* in = S.in[s];
  u16* outp = S.out[s];
  const int R = S.R[s], C = S.C[s], gx = S.gx[s];
  const int local = bid - S.start[s];
  const int by = local / gx, bx = local - by * gx;
  int tx = threadIdx.x & 31, ty = threadIdx.x >> 5;
  int r0 = by * 32, c0 = bx * 32;
#pragma unroll
  for (int p = 0; p < 4; p++) {
    int rr = r0 + ty + p * 8;
    int cc = c0 + tx;
    tile[ty + p * 8][tx] = (cc < C) ? in[(size_t)rr * C + cc] : 0.f;
  }
  __syncthreads();
#pragma unroll
  for (int p = 0; p < 4; p++) {
    outp[(size_t)(c0 + ty + p * 8) * R + r0 + tx] = f2bf(tile[tx][ty + p * 8]);
  }
}

// ---------------- rmsnorm over rows (both norms, one dispatch) -------------
__device__ __forceinline__ void rms_body(const u16* __restrict__ in,
                                         u16* __restrict__ outp,
                                         const float* __restrict__ w,
                                         int D, int sin, int sout, int r) {
  int tid = threadIdx.x;
  int wave = tid >> 6, lane = tid & 63;
  __shared__ float sred[4];
  float vals[6];
  int E = D >> 8;
  float ss = 0.f;
  for (int e = 0; e < E; e++) {
    float v = bf2f(in[(size_t)r * sin + e * 256 + tid]);
    vals[e] = v;
    ss += v * v;
  }
#pragma unroll
  for (int d = 1; d < 64; d <<= 1) ss += __shfl_xor(ss, d, 64);
  if (lane == 0) sred[wave] = ss;
  __syncthreads();
  ss = sred[0] + sred[1] + sred[2] + sred[3];
  float rr = rsqrtf(ss / (float)D + 1e-6f);
  for (int e = 0; e < E; e++)
    outp[(size_t)r * sout + e * 256 + tid] = f2bf(vals[e] * rr * w[e * 256 + tid]);
}

__global__ __launch_bounds__(256) void rmsnorm_dual(const u16* __restrict__ cqkv,
                                                    u16* __restrict__ cq,
                                                    const float* __restrict__ qnw,
                                                    u16* __restrict__ ckv,
                                                    const float* __restrict__ kvnw) {
  int bid = blockIdx.x;
  if (bid < 4096)
    rms_body(cqkv, cq, qnw, 1536, 2176, 1536, bid);
  else
    rms_body(cqkv + 1536, ckv, kvnw, 512, 2176, 512, bid - 4096);
}

// ---------------- GEMM core (m97-structure, gload_lds staging) ------------
// Round-6 measured-best 16x16x32 variant. LDS linear (uniform base +
// lane*16), lane fetches chunk (lane&7)^(lane>>3) of row 32w+8i+(lane>>3):
// LDS slot s of row r holds chunk s^(r&7); swizzled ds_read_b128 fragment
// reads. K must be a multiple of 64.
__device__ __forceinline__ void gemm_body(const u16* __restrict__ A,
                                          const u16* __restrict__ Bt,
                                          void* __restrict__ Cv,
                                          int M, int N, int K, int cf32,
                                          int m0, int n0, u16* As, u16* Bs) {
  const int tid = threadIdx.x;
  const int wave = tid >> 6, lane = tid & 63;
  const int wm = (wave >> 1) * 64, wn = (wave & 1) * 64;
  const int fr = lane & 15, fq = lane >> 4;
  f32x4 acc[4][4] = {};

  const int grow = 32 * wave + (lane >> 3);
  const int gchunk = (lane & 7) ^ (lane >> 3);
  const u16* ag = A + (size_t)(m0 + grow) * K + gchunk * 8;
  const u16* bg = Bt + (size_t)(n0 + grow) * K + gchunk * 8;
  u16* al = As + wave * 2048;
  u16* bl = Bs + wave * 2048;

  const u16* ard[2][4];
  const u16* brd[2][4];
#pragma unroll
  for (int ks = 0; ks < 2; ks++)
#pragma unroll
    for (int i = 0; i < 4; i++) {
      int ra = wm + 16 * i + fr;
      ard[ks][i] = As + ra * 64 + (((fq + ks * 4) ^ (ra & 7)) << 3);
      int rb = wn + 16 * i + fr;
      brd[ks][i] = Bs + rb * 64 + (((fq + ks * 4) ^ (rb & 7)) << 3);
    }

  for (int k0 = 0; k0 < K; k0 += 64) {
    if (k0) __syncthreads();
#pragma unroll
    for (int i = 0; i < 4; i++) {
      gload16(ag + k0 + (size_t)i * 8 * K, al + i * 512);
      gload16(bg + k0 + (size_t)i * 8 * K, bl + i * 512);
    }
    __syncthreads();
#pragma unroll
    for (int ks = 0; ks < 2; ks++) {
      bf16x8 af[4], bf[4];
#pragma unroll
      for (int i = 0; i < 4; i++) {
        af[i] = *(const bf16x8*)ard[ks][i];
        bf[i] = *(const bf16x8*)brd[ks][i];
      }
#pragma unroll
      for (int i = 0; i < 4; i++)
#pragma unroll
        for (int j = 0; j < 4; j++)
          acc[i][j] = __builtin_amdgcn_mfma_f32_16x16x32_bf16(af[i], bf[j], acc[i][j], 0, 0, 0);
    }
  }
  if (cf32) {
    float* C = (float*)Cv;
#pragma unroll
    for (int i = 0; i < 4; i++)
#pragma unroll
      for (int j = 0; j < 4; j++)
#pragma unroll
        for (int r = 0; r < 4; r++)
          C[(size_t)(m0 + wm + 16 * i + fq * 4 + r) * N + n0 + wn + 16 * j + fr] = acc[i][j][r];
  } else {
    u16* C = (u16*)Cv;
#pragma unroll
    for (int i = 0; i < 4; i++)
#pragma unroll
      for (int j = 0; j < 4; j++)
#pragma unroll
        for (int r = 0; r < 4; r++)
          C[(size_t)(m0 + wm + 16 * i + fq * 4 + r) * N + n0 + wn + 16 * j + fr] = f2bf(acc[i][j][r]);
  }
}

__global__ __launch_bounds__(256) void gemm_bt(const u16* __restrict__ A,
                                               const u16* __restrict__ Bt,
                                               void* __restrict__ Cv,
                                               int M, int N, int K, int cf32) {
  __shared__ u16 As[128 * 64];
  __shared__ u16 Bs[128 * 64];
  gemm_body(A, Bt, Cv, M, N, K, cf32, blockIdx.y * 128, blockIdx.x * 128, As, Bs);
}

// Two independent GEMMs fused into one dispatch: blockIdx.z selects params.
__global__ __launch_bounds__(256) void gemm_bt2(const u16* __restrict__ A0,
                                                const u16* __restrict__ B0,
                                                void* __restrict__ C0,
                                                int N0, int K0, int gx0,
                                                const u16* __restrict__ A1,
                                                const u16* __restrict__ B1,
                                                void* __restrict__ C1,
                                                int N1, int K1, int gx1) {
  __shared__ u16 As[128 * 64];
  __shared__ u16 Bs[128 * 64];
  if (blockIdx.z == 0) {
    if ((int)blockIdx.x >= gx0) return;
    gemm_body(A0, B0, C0, 4096, N0, K0, 0, blockIdx.y * 128, blockIdx.x * 128, As, Bs);
  } else {
    if ((int)blockIdx.x >= gx1) return;
    gemm_body(A1, B1, C1, 4096, N1, K1, 0, blockIdx.y * 128, blockIdx.x * 128, As, Bs);
  }
}

// ------------- q pack + kv pack fused into one dispatch --------------------
__global__ __launch_bounds__(256) void pack_dual(const u16* __restrict__ qnr,
                                                 const float* __restrict__ qhw,
                                                 const float* __restrict__ fcos,
                                                 const float* __restrict__ fsin,
                                                 u16* __restrict__ qp,
                                                 const u16* __restrict__ kvu,
                                                 const u16* __restrict__ kvr,
                                                 const float* __restrict__ khw,
                                                 u16* __restrict__ kp,
                                                 u16* __restrict__ vp) {
  __shared__ u16 vsl[128 * 66];
  int bid = blockIdx.x;
  if (bid < 16384) {
    // ---- qpack: head rmsnorm + rope + 1/sqrt(192) scale ----
    int gw = bid * 4 + (threadIdx.x >> 6);
    int lane = threadIdx.x & 63;
    int r = gw >> 4, h = gw & 15;
    int b = r >> 11, t = r & 2047;
    const float sc = 0.07216878364870323f;  // 1/sqrt(192), folded into Q
    float v0 = bf2f(qnr[(size_t)r * 3072 + h * 128 + lane]);
    float v1 = bf2f(qnr[(size_t)r * 3072 + h * 128 + 64 + lane]);
    float ss = v0 * v0 + v1 * v1;
#pragma unroll
    for (int d = 1; d < 64; d <<= 1) ss += __shfl_xor(ss, d, 64);
    float rr = rsqrtf(ss * (1.f / 128.f) + 1e-6f) * sc;
    size_t ob = ((size_t)(b * 16 + h) * 2048 + t) * 192;
    qp[ob + lane] = f2bf(v0 * rr * qhw[lane]);
    qp[ob + 64 + lane] = f2bf(v1 * rr * qhw[64 + lane]);
    if (lane < 32) {
      float a = bf2f(qnr[(size_t)r * 3072 + 2048 + h * 64 + 2 * lane]);
      float bb = bf2f(qnr[(size_t)r * 3072 + 2048 + h * 64 + 2 * lane + 1]);
      float c = fcos[t * 32 + lane], s = fsin[t * 32 + lane];
      qp[ob + 128 + 2 * lane] = f2bf((a * c - bb * s) * sc);
      qp[ob + 129 + 2 * lane] = f2bf((a * s + bb * c) * sc);
    }
  } else {
    // ---- kvpack ----
    int q = bid - 16384;
    int h = q & 15, tile = q >> 4;
    int r0 = tile * 64;
    int b = r0 >> 11;
    int tl = tile & 31;
    int tid = threadIdx.x, wave = tid >> 6, lane = tid & 63;
    int bh = b * 16 + h;
    for (int ii = 0; ii < 16; ii++) {
      int i = wave * 16 + ii;
      int r = r0 + i;
      int t = r & 2047;
      size_t kbase = (size_t)r * 4096 + h * 256;
      float v0 = bf2f(kvu[kbase + lane]);
      float v1 = bf2f(kvu[kbase + 64 + lane]);
      float ss = v0 * v0 + v1 * v1;
#pragma unroll
      for (int d = 1; d < 64; d <<= 1) ss += __shfl_xor(ss, d, 64);
      float rr = rsqrtf(ss * (1.f / 128.f) + 1e-6f);
      size_t ob = ((size_t)bh * 2048 + t) * 192;
      kp[ob + lane] = f2bf(v0 * rr * khw[lane]);
      kp[ob + 64 + lane] = f2bf(v1 * rr * khw[64 + lane]);
      vsl[lane * 66 + i] = kvu[kbase + 128 + lane];
      vsl[(lane + 64) * 66 + i] = kvu[kbase + 192 + lane];
      if (lane < 32) {
        float a = bf2f(kvr[(size_t)r * 2176 + 512 + 2 * lane]);
        float bb = bf2f(kvr[(size_t)r * 2176 + 512 + 2 * lane + 1]);
        float c = fcos[t * 32 + lane], s = fsin[t * 32 + lane];
        kp[ob + 128 + 2 * lane] = f2bf(a * c - bb * s);
        kp[ob + 129 + 2 * lane] = f2bf(a * s + bb * c);
      }
    }
    __syncthreads();
    u16* vb = vp + ((size_t)bh * 32 + tl) * 8192;  // [128 v][64 t] tile
    for (int u = 0; u < 32; u++) {
      int e = u * 256 + tid;
      vb[e] = vsl[(e >> 6) * 66 + (e & 63)];
    }
  }
}

// ---------------- flash attention (causal), split-K across blocks ----------
// Each (qb,bh) is split into s=0 (tiles 0..qb) and s=1 (tiles qb+1..2qb+1):
// 1024 blocks, max 16 tile-steps/block (was 32), LDS 48KB -> 3 blocks/CU.
// LPT decode: idx=bid>>5, qb=15-(idx>>1), s=idx&1 -> heaviest first.
// Inner loop is byte-identical to the round-6 measured best; epilogue stores
// f32 partials (O, m, l) merged by attn_merge (standard flash combine).
__global__ __launch_bounds__(256, 2) void attn_kernel(const u16* __restrict__ Q,
                                                      const u16* __restrict__ Kp,
                                                      const u16* __restrict__ Vt,
                                                      float* __restrict__ PO,
                                                      float* __restrict__ ML) {
  __shared__ u16 Ks[64 * 256];
  __shared__ u16 Vs[128 * 64];
  const int tid = threadIdx.x;
  const int wave = tid >> 6, lane = tid & 63;
  const int n = blockIdx.x;
  const int idx = n >> 5;
  const int qb = 15 - (idx >> 1);
  const int sp = idx & 1;
  const int bh = n & 31;
  const int l31 = lane & 31, half = lane >> 5, xr = lane & 7;

  const char* kgb = (const char*)(Kp + (size_t)bh * T_ * 192);
  const char* vgb = (const char*)(Vt + (size_t)bh * 32 * 8192);
  u16* kw[6];
  u16* vw[4];
#pragma unroll
  for (int c = 0; c < 6; c++) {
    unsigned fo = c * 4096 + tid * 16;
    unsigned row = fo / 384u;
    unsigned chunk = (fo - row * 384) >> 4;
    kw[c] = Ks + row * 256 + ((chunk ^ (row & 7)) << 3);
  }
#pragma unroll
  for (int c = 0; c < 4; c++) {
    unsigned fo = c * 4096 + tid * 16;
    unsigned row = fo >> 7;
    unsigned chunk = (fo >> 4) & 7;
    vw[c] = Vs + row * 64 + ((chunk ^ (row & 7)) << 3);
  }
  const u16* krd0 = Ks + l31 * 256;
  const u16* krd1 = Ks + (32 + l31) * 256;
  const u16* vrd = Vs + l31 * 64;
  i32x4 kreg[6], vreg[4];

  const int qw0 = qb * 128 + wave * 32;
  const int qg = qw0 + l31;
  const int jlo = sp ? qb + 1 : 0;
  const int jhi = sp ? 2 * qb + 1 : qb;

  bf16x8 qf[12];
  {
    const u16* qbp = Q + ((size_t)bh * T_ + qg) * 192 + half * 8;
#pragma unroll
    for (int t = 0; t < 12; t++) qf[t] = *(const bf16x8*)(qbp + t * 16);
  }
  f32x16 oacc[4] = {};
  float m_i = -3.0e38f, l_i = 0.f;

#pragma unroll
  for (int c = 0; c < 6; c++)
    kreg[c] = *(const i32x4*)(kgb + (size_t)jlo * 24576 + c * 4096 + tid * 16);
#pragma unroll
  for (int c = 0; c < 4; c++)
    vreg[c] = *(const i32x4*)(vgb + (size_t)jlo * 16384 + c * 4096 + tid * 16);

  for (int j = jlo; j <= jhi; j++) {
    if (j > jlo) __syncthreads();
#pragma unroll
    for (int c = 0; c < 6; c++) *(i32x4*)kw[c] = kreg[c];
#pragma unroll
    for (int c = 0; c < 4; c++) *(i32x4*)vw[c] = vreg[c];
    __syncthreads();
    if (j < jhi) {
      const char* kg = kgb + (size_t)(j + 1) * 24576;
      const char* vg = vgb + (size_t)(j + 1) * 16384;
#pragma unroll
      for (int c = 0; c < 6; c++) kreg[c] = *(const i32x4*)(kg + c * 4096 + tid * 16);
#pragma unroll
      for (int c = 0; c < 4; c++) vreg[c] = *(const i32x4*)(vg + c * 4096 + tid * 16);
    }
    if (j * 64 > qw0 + 31) continue;

    f32x16 sa[2] = {};
    __builtin_amdgcn_s_setprio(1);
#pragma unroll
    for (int t = 0; t < 12; t++) {
      int sl = ((2 * t + half) ^ xr) << 3;
      bf16x8 a0 = *(const bf16x8*)(krd0 + sl);
      bf16x8 a1 = *(const bf16x8*)(krd1 + sl);
      sa[0] = __builtin_amdgcn_mfma_f32_32x32x16_bf16(a0, qf[t], sa[0], 0, 0, 0);
      sa[1] = __builtin_amdgcn_mfma_f32_32x32x16_bf16(a1, qf[t], sa[1], 0, 0, 0);
    }
    __builtin_amdgcn_s_setprio(0);
    if (j * 64 + 63 > qw0) {
      int kb = j * 64 + 4 * half;
#pragma unroll
      for (int tt = 0; tt < 2; tt++)
#pragma unroll
        for (int r = 0; r < 16; r++) {
          int kk = kb + tt * 32 + (r & 3) + 8 * (r >> 2);
          if (kk > qg) sa[tt][r] = -3.0e38f;
        }
    }
    float mx = -3.0e38f;
#pragma unroll
    for (int r = 0; r < 16; r++) mx = fmaxf(mx, fmaxf(sa[0][r], sa[1][r]));
    mx = fmaxf(mx, __shfl_xor(mx, 32, 64));
    // defer-max: only rescale O when the running max actually grew (>8)
    if (!__all(mx <= m_i + 8.0f)) {
      float mn = fmaxf(m_i, mx);
      float al = exp2f((m_i - mn) * 1.44269504f);
      l_i *= al;
#pragma unroll
      for (int vt = 0; vt < 4; vt++)
#pragma unroll
        for (int r = 0; r < 16; r++) oacc[vt][r] *= al;
      m_i = mn;
    }
    float rs = 0.f;
#pragma unroll
    for (int tt = 0; tt < 2; tt++)
#pragma unroll
      for (int r = 0; r < 16; r++) {
        float p = exp2f((sa[tt][r] - m_i) * 1.44269504f);
        sa[tt][r] = p;
        rs += p;
      }
    rs += __shfl_xor(rs, 32, 64);
    l_i += rs;

    // ---- in-register P -> PV B-fragment via permlane32_swap (T12) ----
    bf16x8 pf[4];
#pragma unroll
    for (int tt = 0; tt < 2; tt++)
#pragma unroll
      for (int s = 0; s < 2; s++) {
        unsigned X0 = pk2(sa[tt][8 * s + 0], sa[tt][8 * s + 1]);
        unsigned X1 = pk2(sa[tt][8 * s + 2], sa[tt][8 * s + 3]);
        unsigned Y0 = pk2(sa[tt][8 * s + 4], sa[tt][8 * s + 5]);
        unsigned Y1 = pk2(sa[tt][8 * s + 6], sa[tt][8 * s + 7]);
        u32x2 r0 = __builtin_amdgcn_permlane32_swap(X0, Y0, false, false);
        u32x2 r1 = __builtin_amdgcn_permlane32_swap(X1, Y1, false, false);
        u32x4 w;
        w.x = r0.x;
        w.y = r1.x;
        w.z = r0.y;
        w.w = r1.y;
        pf[2 * tt + s] = __builtin_bit_cast(bf16x8, w);
      }

    __builtin_amdgcn_s_setprio(1);
#pragma unroll
    for (int t = 0; t < 4; t++) {
#pragma unroll
      for (int vt = 0; vt < 4; vt++) {
        bf16x8 vf = *(const bf16x8*)(vrd + vt * 32 * 64 + (((2 * t + half) ^ xr) << 3));
        oacc[vt] = __builtin_amdgcn_mfma_f32_32x32x16_bf16(vf, pf[t], oacc[vt], 0, 0, 0);
      }
    }
    __builtin_amdgcn_s_setprio(0);
  }

  // ---- store f32 partials: PO[sp][bh*2048+t][128], ML[sp][bh*2048+t] ----
  float* prow = PO + (size_t)sp * 8388608 + ((size_t)bh * 2048 + qg) * 128;
#pragma unroll
  for (int vt = 0; vt < 4; vt++)
#pragma unroll
    for (int qd = 0; qd < 4; qd++) {
      f32x4 o4;
      o4.x = oacc[vt][qd * 4 + 0];
      o4.y = oacc[vt][qd * 4 + 1];
      o4.z = oacc[vt][qd * 4 + 2];
      o4.w = oacc[vt][qd * 4 + 3];
      *(f32x4*)(prow + vt * 32 + qd * 8 + 4 * half) = o4;
    }
  if (half == 0) {
    f32x2 mv;
    mv.x = m_i;
    mv.y = l_i;
    *(f32x2*)(ML + ((size_t)sp * 65536 + (size_t)bh * 2048 + qg) * 2) = mv;
  }
}

// Flash combine of the two splits: O = (a0*O0 + a1*O1) / (a0*l0 + a1*l1).
__global__ __launch_bounds__(256) void attn_merge(const float* __restrict__ PO,
                                                  const float* __restrict__ ML,
                                                  u16* __restrict__ O) {
  size_t e = ((size_t)blockIdx.x * 256 + threadIdx.x) * 4;
  int row = (int)(e >> 7);
  int col = (int)(e & 127);
  float m0 = ML[(size_t)row * 2], l0 = ML[(size_t)row * 2 + 1];
  float m1 = ML[131072 + (size_t)row * 2], l1 = ML[131072 + (size_t)row * 2 + 1];
  float m = fmaxf(m0, m1);
  float a0 = exp2f((m0 - m) * 1.44269504f);
  float a1 = exp2f((m1 - m) * 1.44269504f);
  float inv = 1.f / (a0 * l0 + a1 * l1);
  a0 *= inv;
  a1 *= inv;
  f32x4 o0 = *(const f32x4*)(PO + (size_t)row * 128 + col);
  f32x4 o1 = *(const f32x4*)(PO + 8388608 + (size_t)row * 128 + col);
  int bh = row >> 11, t = row & 2047;
  int b = bh >> 4, h = bh & 15;
  u16* op = O + ((size_t)(b * 2048 + t)) * 2048 + h * 128 + col;
  uint2 pk;
  pk.x = pk2(a0 * o0.x + a1 * o1.x, a0 * o0.y + a1 * o1.y);
  pk.y = pk2(a0 * o0.z + a1 * o1.z, a0 * o0.w + a1 * o1.w);
  *(uint2*)op = pk;
}

extern "C" void kernel_launch(void* const* d_in, const int* in_sizes, int n_in,
                              void* d_out, int out_size, void* d_ws, size_t ws_size,
                              hipStream_t stream) {
  const float* x    = (const float*)d_in[0];
  const float* fcos = (const float*)d_in[1];
  const float* fsin = (const float*)d_in[2];
  const float* wqd  = (const float*)d_in[3];
  const float* qnw  = (const float*)d_in[4];
  const float* wqun = (const float*)d_in[5];
  const float* wqur = (const float*)d_in[6];
  const float* wkvd = (const float*)d_in[7];
  const float* kvnw = (const float*)d_in[8];
  const float* wkvu = (const float*)d_in[9];
  const float* qhnw = (const float*)d_in[10];
  const float* khnw = (const float*)d_in[11];
  const float* wwo  = (const float*)d_in[12];
  float* out = (float*)d_out;
  char* ws = (char*)d_ws;

  size_t off = 0;
  auto alloc = [&](size_t elems) -> u16* {
    u16* p = (u16*)(ws + off);
    off += ((elems * 2 + 255) & ~(size_t)255);
    return p;
  };
  u16* x16   = alloc(4096ull * 2048);
  u16* bqkvd = alloc(2176ull * 2048);  // fused q_down(1536) + kv_down(640)
  u16* bqu   = alloc(3072ull * 1536);  // merged q_up
  u16* bkvu  = alloc(4096ull * 512);
  u16* bwo   = alloc(2048ull * 2048);
  u16* cqkv  = alloc(4096ull * 2176);  // fused down-proj output
  u16* cq    = alloc(4096ull * 1536);
  u16* qnr   = alloc(4096ull * 3072);
  u16* ckv   = alloc(4096ull * 512);
  u16* kvu   = alloc(4096ull * 4096);
  u16* qp    = alloc(32ull * 2048 * 192);
  u16* kp    = alloc(32ull * 2048 * 192);
  u16* vp    = alloc(32ull * 2048 * 128);
  u16* ao    = alloc(4096ull * 2048);
  if (ws_size < off) return;

  // attn partials alias the cqkv..kvu region (93.4MB), dead after pack_dual:
  // PO = 2 splits x 32 bh x 2048 t x 128 f32 (64MB), ML = 2x32x2048 f32x2 (1MB)
  float* PO = (float*)cqkv;
  float* ML = (float*)((char*)cqkv + 67108864);

  cast_f32_bf16<<<8192, 256, 0, stream>>>(x, x16, 4096 * 2048);

  // six weight transposes, one dispatch
  CTSegs S;
  S.in[0] = wqd;  S.out[0] = bqkvd;                 S.R[0] = 2048; S.C[0] = 1536; S.gx[0] = 48;
  S.in[1] = wkvd; S.out[1] = bqkvd + 1536ull * 2048; S.R[1] = 2048; S.C[1] = 576;  S.gx[1] = 20;
  S.in[2] = wqun; S.out[2] = bqu;                   S.R[2] = 1536; S.C[2] = 2048; S.gx[2] = 64;
  S.in[3] = wqur; S.out[3] = bqu + 2048ull * 1536;  S.R[3] = 1536; S.C[3] = 1024; S.gx[3] = 32;
  S.in[4] = wkvu; S.out[4] = bkvu;                  S.R[4] = 512;  S.C[4] = 4096; S.gx[4] = 128;
  S.in[5] = wwo;  S.out[5] = bwo;                   S.R[5] = 2048; S.C[5] = 2048; S.gx[5] = 64;
  int tot = 0;
  int gy[6] = {64, 64, 48, 48, 16, 64};
  for (int k = 0; k < 6; k++) { S.start[k] = tot; tot += S.gx[k] * gy[k]; }
  castT_multi<<<tot, 256, 0, stream>>>(S);

  gemm_bt<<<dim3(17, 32), 256, 0, stream>>>(x16, bqkvd, cqkv, 4096, 2176, 2048, 0);
  rmsnorm_dual<<<8192, 256, 0, stream>>>(cqkv, cq, qnw, ckv, kvnw);
  // q_up (K=1536) and kv_up (K=512) fused: long-K z=0 first, short-K backfills
  gemm_bt2<<<dim3(32, 32, 2), 256, 0, stream>>>(cq, bqu, qnr, 3072, 1536, 24,
                                                ckv, bkvu, kvu, 4096, 512, 32);
  pack_dual<<<17408, 256, 0, stream>>>(qnr, qhnw, fcos, fsin, qp,
                                       kvu, cqkv + 1536, khnw, kp, vp);
  attn_kernel<<<1024, 256, 0, stream>>>(qp, kp, vp, PO, ML);
  attn_merge<<<8192, 256, 0, stream>>>(PO, ML, ao);
  gemm_bt<<<dim3(16, 32), 256, 0, stream>>>(ao, bwo, out, 4096, 2048, 2048, 1);
}

// Round 10
// 442.612 us; speedup vs baseline: 1.4762x; 1.0201x over previous
//
#include <hip/hip_runtime.h>
#include <hip/hip_bf16.h>
#include <stdint.h>

typedef unsigned short u16;
typedef __bf16 bf16x8 __attribute__((ext_vector_type(8)));
typedef __attribute__((ext_vector_type(2))) float f32x2;
typedef __attribute__((ext_vector_type(4))) float f32x4;
typedef __attribute__((ext_vector_type(16))) float f32x16;
typedef __attribute__((ext_vector_type(4))) unsigned short u16x4;
typedef __attribute__((ext_vector_type(4))) int i32x4;
typedef __attribute__((ext_vector_type(2))) unsigned u32x2;
typedef __attribute__((ext_vector_type(4))) unsigned u32x4;

#define T_ 2048

__device__ __forceinline__ u16 f2bf(float f) {
  __hip_bfloat16 h = __float2bfloat16(f);
  return __builtin_bit_cast(u16, h);
}
__device__ __forceinline__ float bf2f(u16 u) {
  __hip_bfloat16 h = __builtin_bit_cast(__hip_bfloat16, u);
  return __bfloat162float(h);
}
__device__ __forceinline__ unsigned pk2(float a, float b) {
  return (unsigned)f2bf(a) | ((unsigned)f2bf(b) << 16);
}
__device__ __forceinline__ void gload16(const u16* g, u16* l) {
  __builtin_amdgcn_global_load_lds((const __attribute__((address_space(1))) void*)g,
                                   (__attribute__((address_space(3))) void*)l, 16, 0, 0);
}

// ---------------- casts ----------------
__global__ __launch_bounds__(256) void cast_f32_bf16(const float* __restrict__ in,
                                                     u16* __restrict__ outp, int n) {
  int i = (blockIdx.x * 256 + threadIdx.x) * 4;
  if (i < n) {
    f32x4 v = *(const f32x4*)(in + i);
    u16x4 o;
    o.x = f2bf(v.x); o.y = f2bf(v.y); o.z = f2bf(v.z); o.w = f2bf(v.w);
    *(u16x4*)(outp + i) = o;
  }
}

// Weight transposes via segment table. Per segment: in fp32 [R][C] ->
// out bf16 [Cpad][R]; cols >= C write 0. Unused slots: start = INT_MAX.
struct CTSegs {
  const float* in[6];
  u16* out[6];
  int R[6], C[6], gx[6], start[6];
};
__device__ __forceinline__ void castT_body(const CTSegs& S, int bid, float* tile /*32x33*/) {
  int s = 0;
#pragma unroll
  for (int k = 1; k < 6; k++)
    if (bid >= S.start[k]) s = k;
  const float* in = S.in[s];
  u16* outp = S.out[s];
  const int R = S.R[s], C = S.C[s], gx = S.gx[s];
  const int local = bid - S.start[s];
  const int by = local / gx, bx = local - by * gx;
  int tx = threadIdx.x & 31, ty = threadIdx.x >> 5;
  int r0 = by * 32, c0 = bx * 32;
#pragma unroll
  for (int p = 0; p < 4; p++) {
    int rr = r0 + ty + p * 8;
    int cc = c0 + tx;
    tile[(ty + p * 8) * 33 + tx] = (cc < C) ? in[(size_t)rr * C + cc] : 0.f;
  }
  __syncthreads();
#pragma unroll
  for (int p = 0; p < 4; p++) {
    outp[(size_t)(c0 + ty + p * 8) * R + r0 + tx] = f2bf(tile[tx * 33 + ty + p * 8]);
  }
}

__global__ __launch_bounds__(256) void castT_multi(CTSegs S) {
  __shared__ float tile[32 * 33];
  castT_body(S, blockIdx.x, tile);
}

// ---------------- rmsnorm over rows (both norms, one dispatch) -------------
__device__ __forceinline__ void rms_body(const u16* __restrict__ in,
                                         u16* __restrict__ outp,
                                         const float* __restrict__ w,
                                         int D, int sin, int sout, int r) {
  int tid = threadIdx.x;
  int wave = tid >> 6, lane = tid & 63;
  __shared__ float sred[4];
  float vals[6];
  int E = D >> 8;
  float ss = 0.f;
  for (int e = 0; e < E; e++) {
    float v = bf2f(in[(size_t)r * sin + e * 256 + tid]);
    vals[e] = v;
    ss += v * v;
  }
#pragma unroll
  for (int d = 1; d < 64; d <<= 1) ss += __shfl_xor(ss, d, 64);
  if (lane == 0) sred[wave] = ss;
  __syncthreads();
  ss = sred[0] + sred[1] + sred[2] + sred[3];
  float rr = rsqrtf(ss / (float)D + 1e-6f);
  for (int e = 0; e < E; e++)
    outp[(size_t)r * sout + e * 256 + tid] = f2bf(vals[e] * rr * w[e * 256 + tid]);
}

__global__ __launch_bounds__(256) void rmsnorm_dual(const u16* __restrict__ cqkv,
                                                    u16* __restrict__ cq,
                                                    const float* __restrict__ qnw,
                                                    u16* __restrict__ ckv,
                                                    const float* __restrict__ kvnw) {
  int bid = blockIdx.x;
  if (bid < 4096)
    rms_body(cqkv, cq, qnw, 1536, 2176, 1536, bid);
  else
    rms_body(cqkv + 1536, ckv, kvnw, 512, 2176, 512, bid - 4096);
}

// ---------------- GEMM core (m97-structure, gload_lds staging) ------------
// Round-6 measured-best 16x16x32 variant. LDS linear (uniform base +
// lane*16), lane fetches chunk (lane&7)^(lane>>3) of row 32w+8i+(lane>>3):
// LDS slot s of row r holds chunk s^(r&7); swizzled ds_read_b128 fragment
// reads. K must be a multiple of 64.
__device__ __forceinline__ void gemm_body(const u16* __restrict__ A,
                                          const u16* __restrict__ Bt,
                                          void* __restrict__ Cv,
                                          int M, int N, int K, int cf32,
                                          int m0, int n0, u16* As, u16* Bs) {
  const int tid = threadIdx.x;
  const int wave = tid >> 6, lane = tid & 63;
  const int wm = (wave >> 1) * 64, wn = (wave & 1) * 64;
  const int fr = lane & 15, fq = lane >> 4;
  f32x4 acc[4][4] = {};

  const int grow = 32 * wave + (lane >> 3);
  const int gchunk = (lane & 7) ^ (lane >> 3);
  const u16* ag = A + (size_t)(m0 + grow) * K + gchunk * 8;
  const u16* bg = Bt + (size_t)(n0 + grow) * K + gchunk * 8;
  u16* al = As + wave * 2048;
  u16* bl = Bs + wave * 2048;

  const u16* ard[2][4];
  const u16* brd[2][4];
#pragma unroll
  for (int ks = 0; ks < 2; ks++)
#pragma unroll
    for (int i = 0; i < 4; i++) {
      int ra = wm + 16 * i + fr;
      ard[ks][i] = As + ra * 64 + (((fq + ks * 4) ^ (ra & 7)) << 3);
      int rb = wn + 16 * i + fr;
      brd[ks][i] = Bs + rb * 64 + (((fq + ks * 4) ^ (rb & 7)) << 3);
    }

  for (int k0 = 0; k0 < K; k0 += 64) {
    if (k0) __syncthreads();
#pragma unroll
    for (int i = 0; i < 4; i++) {
      gload16(ag + k0 + (size_t)i * 8 * K, al + i * 512);
      gload16(bg + k0 + (size_t)i * 8 * K, bl + i * 512);
    }
    __syncthreads();
#pragma unroll
    for (int ks = 0; ks < 2; ks++) {
      bf16x8 af[4], bf[4];
#pragma unroll
      for (int i = 0; i < 4; i++) {
        af[i] = *(const bf16x8*)ard[ks][i];
        bf[i] = *(const bf16x8*)brd[ks][i];
      }
#pragma unroll
      for (int i = 0; i < 4; i++)
#pragma unroll
        for (int j = 0; j < 4; j++)
          acc[i][j] = __builtin_amdgcn_mfma_f32_16x16x32_bf16(af[i], bf[j], acc[i][j], 0, 0, 0);
    }
  }
  if (cf32) {
    float* C = (float*)Cv;
#pragma unroll
    for (int i = 0; i < 4; i++)
#pragma unroll
      for (int j = 0; j < 4; j++)
#pragma unroll
        for (int r = 0; r < 4; r++)
          C[(size_t)(m0 + wm + 16 * i + fq * 4 + r) * N + n0 + wn + 16 * j + fr] = acc[i][j][r];
  } else {
    u16* C = (u16*)Cv;
#pragma unroll
    for (int i = 0; i < 4; i++)
#pragma unroll
      for (int j = 0; j < 4; j++)
#pragma unroll
        for (int r = 0; r < 4; r++)
          C[(size_t)(m0 + wm + 16 * i + fq * 4 + r) * N + n0 + wn + 16 * j + fr] = f2bf(acc[i][j][r]);
  }
}

__global__ __launch_bounds__(256) void gemm_bt(const u16* __restrict__ A,
                                               const u16* __restrict__ Bt,
                                               void* __restrict__ Cv,
                                               int M, int N, int K, int cf32) {
  __shared__ u16 As[128 * 64];
  __shared__ u16 Bs[128 * 64];
  gemm_body(A, Bt, Cv, M, N, K, cf32, blockIdx.y * 128, blockIdx.x * 128, As, Bs);
}

// gemm1 (x @ [q_down|kv_down], 544 tiles) fused with the 4 weight-transpose
// segments that do NOT feed it (bqu/bkvu/bwo): gemm tiles dispatch first,
// castT blocks backfill the machine during gemm1's tail.
__global__ __launch_bounds__(256) void gemm1_castT(const u16* __restrict__ A,
                                                   const u16* __restrict__ Bt,
                                                   u16* __restrict__ C,
                                                   CTSegs S) {
  __shared__ u16 As[128 * 64];
  __shared__ u16 Bs[128 * 64];
  int bid = blockIdx.x;
  if (bid < 544) {
    gemm_body(A, Bt, C, 4096, 2176, 2048, 0, (bid / 17) * 128, (bid % 17) * 128, As, Bs);
  } else {
    castT_body(S, bid - 544, (float*)As);  // 4224B scratch inside As
  }
}

// Two independent GEMMs fused into one dispatch: blockIdx.z selects params.
__global__ __launch_bounds__(256) void gemm_bt2(const u16* __restrict__ A0,
                                                const u16* __restrict__ B0,
                                                void* __restrict__ C0,
                                                int N0, int K0, int gx0,
                                                const u16* __restrict__ A1,
                                                const u16* __restrict__ B1,
                                                void* __restrict__ C1,
                                                int N1, int K1, int gx1) {
  __shared__ u16 As[128 * 64];
  __shared__ u16 Bs[128 * 64];
  if (blockIdx.z == 0) {
    if ((int)blockIdx.x >= gx0) return;
    gemm_body(A0, B0, C0, 4096, N0, K0, 0, blockIdx.y * 128, blockIdx.x * 128, As, Bs);
  } else {
    if ((int)blockIdx.x >= gx1) return;
    gemm_body(A1, B1, C1, 4096, N1, K1, 0, blockIdx.y * 128, blockIdx.x * 128, As, Bs);
  }
}

// ------------- q pack + kv pack fused into one dispatch --------------------
__global__ __launch_bounds__(256) void pack_dual(const u16* __restrict__ qnr,
                                                 const float* __restrict__ qhw,
                                                 const float* __restrict__ fcos,
                                                 const float* __restrict__ fsin,
                                                 u16* __restrict__ qp,
                                                 const u16* __restrict__ kvu,
                                                 const u16* __restrict__ kvr,
                                                 const float* __restrict__ khw,
                                                 u16* __restrict__ kp,
                                                 u16* __restrict__ vp) {
  __shared__ u16 vsl[128 * 66];
  int bid = blockIdx.x;
  if (bid < 16384) {
    // ---- qpack: head rmsnorm + rope + 1/sqrt(192) scale ----
    int gw = bid * 4 + (threadIdx.x >> 6);
    int lane = threadIdx.x & 63;
    int r = gw >> 4, h = gw & 15;
    int b = r >> 11, t = r & 2047;
    const float sc = 0.07216878364870323f;  // 1/sqrt(192), folded into Q
    float v0 = bf2f(qnr[(size_t)r * 3072 + h * 128 + lane]);
    float v1 = bf2f(qnr[(size_t)r * 3072 + h * 128 + 64 + lane]);
    float ss = v0 * v0 + v1 * v1;
#pragma unroll
    for (int d = 1; d < 64; d <<= 1) ss += __shfl_xor(ss, d, 64);
    float rr = rsqrtf(ss * (1.f / 128.f) + 1e-6f) * sc;
    size_t ob = ((size_t)(b * 16 + h) * 2048 + t) * 192;
    qp[ob + lane] = f2bf(v0 * rr * qhw[lane]);
    qp[ob + 64 + lane] = f2bf(v1 * rr * qhw[64 + lane]);
    if (lane < 32) {
      float a = bf2f(qnr[(size_t)r * 3072 + 2048 + h * 64 + 2 * lane]);
      float bb = bf2f(qnr[(size_t)r * 3072 + 2048 + h * 64 + 2 * lane + 1]);
      float c = fcos[t * 32 + lane], s = fsin[t * 32 + lane];
      qp[ob + 128 + 2 * lane] = f2bf((a * c - bb * s) * sc);
      qp[ob + 129 + 2 * lane] = f2bf((a * s + bb * c) * sc);
    }
  } else {
    // ---- kvpack ----
    int q = bid - 16384;
    int h = q & 15, tile = q >> 4;
    int r0 = tile * 64;
    int b = r0 >> 11;
    int tl = tile & 31;
    int tid = threadIdx.x, wave = tid >> 6, lane = tid & 63;
    int bh = b * 16 + h;
    for (int ii = 0; ii < 16; ii++) {
      int i = wave * 16 + ii;
      int r = r0 + i;
      int t = r & 2047;
      size_t kbase = (size_t)r * 4096 + h * 256;
      float v0 = bf2f(kvu[kbase + lane]);
      float v1 = bf2f(kvu[kbase + 64 + lane]);
      float ss = v0 * v0 + v1 * v1;
#pragma unroll
      for (int d = 1; d < 64; d <<= 1) ss += __shfl_xor(ss, d, 64);
      float rr = rsqrtf(ss * (1.f / 128.f) + 1e-6f);
      size_t ob = ((size_t)bh * 2048 + t) * 192;
      kp[ob + lane] = f2bf(v0 * rr * khw[lane]);
      kp[ob + 64 + lane] = f2bf(v1 * rr * khw[64 + lane]);
      vsl[lane * 66 + i] = kvu[kbase + 128 + lane];
      vsl[(lane + 64) * 66 + i] = kvu[kbase + 192 + lane];
      if (lane < 32) {
        float a = bf2f(kvr[(size_t)r * 2176 + 512 + 2 * lane]);
        float bb = bf2f(kvr[(size_t)r * 2176 + 512 + 2 * lane + 1]);
        float c = fcos[t * 32 + lane], s = fsin[t * 32 + lane];
        kp[ob + 128 + 2 * lane] = f2bf(a * c - bb * s);
        kp[ob + 129 + 2 * lane] = f2bf(a * s + bb * c);
      }
    }
    __syncthreads();
    u16* vb = vp + ((size_t)bh * 32 + tl) * 8192;  // [128 v][64 t] tile
    for (int u = 0; u < 32; u++) {
      int e = u * 256 + tid;
      vb[e] = vsl[(e >> 6) * 66 + (e & 63)];
    }
  }
}

// ---------------- flash attention (causal), split-K across blocks ----------
// 1024 blocks, max 16 tile-steps/block; LPT decode. LDS 40KB exactly
// (Ks stride 192 u16: the K tile is 64x192, the old 256 stride wasted 8KB;
// both strides are 0 mod 128B so bank/swizzle behavior is identical) ->
// 4 blocks/CU co-resident (4 x 40960 = 160KB). Inner loop otherwise
// byte-identical to the round-6/9 measured best; f32 partials merged by
// attn_merge.
__global__ __launch_bounds__(256, 2) void attn_kernel(const u16* __restrict__ Q,
                                                      const u16* __restrict__ Kp,
                                                      const u16* __restrict__ Vt,
                                                      float* __restrict__ PO,
                                                      float* __restrict__ ML) {
  __shared__ u16 Ks[64 * 192];
  __shared__ u16 Vs[128 * 64];
  const int tid = threadIdx.x;
  const int wave = tid >> 6, lane = tid & 63;
  const int n = blockIdx.x;
  const int idx = n >> 5;
  const int qb = 15 - (idx >> 1);
  const int sp = idx & 1;
  const int bh = n & 31;
  const int l31 = lane & 31, half = lane >> 5, xr = lane & 7;

  const char* kgb = (const char*)(Kp + (size_t)bh * T_ * 192);
  const char* vgb = (const char*)(Vt + (size_t)bh * 32 * 8192);
  u16* kw[6];
  u16* vw[4];
#pragma unroll
  for (int c = 0; c < 6; c++) {
    unsigned fo = c * 4096 + tid * 16;
    unsigned row = fo / 384u;
    unsigned chunk = (fo - row * 384) >> 4;
    kw[c] = Ks + row * 192 + ((chunk ^ (row & 7)) << 3);
  }
#pragma unroll
  for (int c = 0; c < 4; c++) {
    unsigned fo = c * 4096 + tid * 16;
    unsigned row = fo >> 7;
    unsigned chunk = (fo >> 4) & 7;
    vw[c] = Vs + row * 64 + ((chunk ^ (row & 7)) << 3);
  }
  const u16* krd0 = Ks + l31 * 192;
  const u16* krd1 = Ks + (32 + l31) * 192;
  const u16* vrd = Vs + l31 * 64;
  i32x4 kreg[6], vreg[4];

  const int qw0 = qb * 128 + wave * 32;
  const int qg = qw0 + l31;
  const int jlo = sp ? qb + 1 : 0;
  const int jhi = sp ? 2 * qb + 1 : qb;

  bf16x8 qf[12];
  {
    const u16* qbp = Q + ((size_t)bh * T_ + qg) * 192 + half * 8;
#pragma unroll
    for (int t = 0; t < 12; t++) qf[t] = *(const bf16x8*)(qbp + t * 16);
  }
  f32x16 oacc[4] = {};
  float m_i = -3.0e38f, l_i = 0.f;

#pragma unroll
  for (int c = 0; c < 6; c++)
    kreg[c] = *(const i32x4*)(kgb + (size_t)jlo * 24576 + c * 4096 + tid * 16);
#pragma unroll
  for (int c = 0; c < 4; c++)
    vreg[c] = *(const i32x4*)(vgb + (size_t)jlo * 16384 + c * 4096 + tid * 16);

  for (int j = jlo; j <= jhi; j++) {
    if (j > jlo) __syncthreads();
#pragma unroll
    for (int c = 0; c < 6; c++) *(i32x4*)kw[c] = kreg[c];
#pragma unroll
    for (int c = 0; c < 4; c++) *(i32x4*)vw[c] = vreg[c];
    __syncthreads();
    if (j < jhi) {
      const char* kg = kgb + (size_t)(j + 1) * 24576;
      const char* vg = vgb + (size_t)(j + 1) * 16384;
#pragma unroll
      for (int c = 0; c < 6; c++) kreg[c] = *(const i32x4*)(kg + c * 4096 + tid * 16);
#pragma unroll
      for (int c = 0; c < 4; c++) vreg[c] = *(const i32x4*)(vg + c * 4096 + tid * 16);
    }
    if (j * 64 > qw0 + 31) continue;

    f32x16 sa[2] = {};
    __builtin_amdgcn_s_setprio(1);
#pragma unroll
    for (int t = 0; t < 12; t++) {
      int sl = ((2 * t + half) ^ xr) << 3;
      bf16x8 a0 = *(const bf16x8*)(krd0 + sl);
      bf16x8 a1 = *(const bf16x8*)(krd1 + sl);
      sa[0] = __builtin_amdgcn_mfma_f32_32x32x16_bf16(a0, qf[t], sa[0], 0, 0, 0);
      sa[1] = __builtin_amdgcn_mfma_f32_32x32x16_bf16(a1, qf[t], sa[1], 0, 0, 0);
    }
    __builtin_amdgcn_s_setprio(0);
    if (j * 64 + 63 > qw0) {
      int kb = j * 64 + 4 * half;
#pragma unroll
      for (int tt = 0; tt < 2; tt++)
#pragma unroll
        for (int r = 0; r < 16; r++) {
          int kk = kb + tt * 32 + (r & 3) + 8 * (r >> 2);
          if (kk > qg) sa[tt][r] = -3.0e38f;
        }
    }
    float mx = -3.0e38f;
#pragma unroll
    for (int r = 0; r < 16; r++) mx = fmaxf(mx, fmaxf(sa[0][r], sa[1][r]));
    mx = fmaxf(mx, __shfl_xor(mx, 32, 64));
    // defer-max: only rescale O when the running max actually grew (>8)
    if (!__all(mx <= m_i + 8.0f)) {
      float mn = fmaxf(m_i, mx);
      float al = exp2f((m_i - mn) * 1.44269504f);
      l_i *= al;
#pragma unroll
      for (int vt = 0; vt < 4; vt++)
#pragma unroll
        for (int r = 0; r < 16; r++) oacc[vt][r] *= al;
      m_i = mn;
    }
    float rs = 0.f;
#pragma unroll
    for (int tt = 0; tt < 2; tt++)
#pragma unroll
      for (int r = 0; r < 16; r++) {
        float p = exp2f((sa[tt][r] - m_i) * 1.44269504f);
        sa[tt][r] = p;
        rs += p;
      }
    rs += __shfl_xor(rs, 32, 64);
    l_i += rs;

    // ---- in-register P -> PV B-fragment via permlane32_swap (T12) ----
    bf16x8 pf[4];
#pragma unroll
    for (int tt = 0; tt < 2; tt++)
#pragma unroll
      for (int s = 0; s < 2; s++) {
        unsigned X0 = pk2(sa[tt][8 * s + 0], sa[tt][8 * s + 1]);
        unsigned X1 = pk2(sa[tt][8 * s + 2], sa[tt][8 * s + 3]);
        unsigned Y0 = pk2(sa[tt][8 * s + 4], sa[tt][8 * s + 5]);
        unsigned Y1 = pk2(sa[tt][8 * s + 6], sa[tt][8 * s + 7]);
        u32x2 r0 = __builtin_amdgcn_permlane32_swap(X0, Y0, false, false);
        u32x2 r1 = __builtin_amdgcn_permlane32_swap(X1, Y1, false, false);
        u32x4 w;
        w.x = r0.x;
        w.y = r1.x;
        w.z = r0.y;
        w.w = r1.y;
        pf[2 * tt + s] = __builtin_bit_cast(bf16x8, w);
      }

    __builtin_amdgcn_s_setprio(1);
#pragma unroll
    for (int t = 0; t < 4; t++) {
#pragma unroll
      for (int vt = 0; vt < 4; vt++) {
        bf16x8 vf = *(const bf16x8*)(vrd + vt * 32 * 64 + (((2 * t + half) ^ xr) << 3));
        oacc[vt] = __builtin_amdgcn_mfma_f32_32x32x16_bf16(vf, pf[t], oacc[vt], 0, 0, 0);
      }
    }
    __builtin_amdgcn_s_setprio(0);
  }

  // ---- store f32 partials: PO[sp][bh*2048+t][128], ML[sp][bh*2048+t] ----
  float* prow = PO + (size_t)sp * 8388608 + ((size_t)bh * 2048 + qg) * 128;
#pragma unroll
  for (int vt = 0; vt < 4; vt++)
#pragma unroll
    for (int qd = 0; qd < 4; qd++) {
      f32x4 o4;
      o4.x = oacc[vt][qd * 4 + 0];
      o4.y = oacc[vt][qd * 4 + 1];
      o4.z = oacc[vt][qd * 4 + 2];
      o4.w = oacc[vt][qd * 4 + 3];
      *(f32x4*)(prow + vt * 32 + qd * 8 + 4 * half) = o4;
    }
  if (half == 0) {
    f32x2 mv;
    mv.x = m_i;
    mv.y = l_i;
    *(f32x2*)(ML + ((size_t)sp * 65536 + (size_t)bh * 2048 + qg) * 2) = mv;
  }
}

// Flash combine of the two splits: O = (a0*O0 + a1*O1) / (a0*l0 + a1*l1).
__global__ __launch_bounds__(256) void attn_merge(const float* __restrict__ PO,
                                                  const float* __restrict__ ML,
                                                  u16* __restrict__ O) {
  size_t e = ((size_t)blockIdx.x * 256 + threadIdx.x) * 4;
  int row = (int)(e >> 7);
  int col = (int)(e & 127);
  float m0 = ML[(size_t)row * 2], l0 = ML[(size_t)row * 2 + 1];
  float m1 = ML[131072 + (size_t)row * 2], l1 = ML[131072 + (size_t)row * 2 + 1];
  float m = fmaxf(m0, m1);
  float a0 = exp2f((m0 - m) * 1.44269504f);
  float a1 = exp2f((m1 - m) * 1.44269504f);
  float inv = 1.f / (a0 * l0 + a1 * l1);
  a0 *= inv;
  a1 *= inv;
  f32x4 o0 = *(const f32x4*)(PO + (size_t)row * 128 + col);
  f32x4 o1 = *(const f32x4*)(PO + 8388608 + (size_t)row * 128 + col);
  int bh = row >> 11, t = row & 2047;
  int b = bh >> 4, h = bh & 15;
  u16* op = O + ((size_t)(b * 2048 + t)) * 2048 + h * 128 + col;
  uint2 pk;
  pk.x = pk2(a0 * o0.x + a1 * o1.x, a0 * o0.y + a1 * o1.y);
  pk.y = pk2(a0 * o0.z + a1 * o1.z, a0 * o0.w + a1 * o1.w);
  *(uint2*)op = pk;
}

extern "C" void kernel_launch(void* const* d_in, const int* in_sizes, int n_in,
                              void* d_out, int out_size, void* d_ws, size_t ws_size,
                              hipStream_t stream) {
  const float* x    = (const float*)d_in[0];
  const float* fcos = (const float*)d_in[1];
  const float* fsin = (const float*)d_in[2];
  const float* wqd  = (const float*)d_in[3];
  const float* qnw  = (const float*)d_in[4];
  const float* wqun = (const float*)d_in[5];
  const float* wqur = (const float*)d_in[6];
  const float* wkvd = (const float*)d_in[7];
  const float* kvnw = (const float*)d_in[8];
  const float* wkvu = (const float*)d_in[9];
  const float* qhnw = (const float*)d_in[10];
  const float* khnw = (const float*)d_in[11];
  const float* wwo  = (const float*)d_in[12];
  float* out = (float*)d_out;
  char* ws = (char*)d_ws;

  size_t off = 0;
  auto alloc = [&](size_t elems) -> u16* {
    u16* p = (u16*)(ws + off);
    off += ((elems * 2 + 255) & ~(size_t)255);
    return p;
  };
  u16* x16   = alloc(4096ull * 2048);
  u16* bqkvd = alloc(2176ull * 2048);  // fused q_down(1536) + kv_down(640)
  u16* bqu   = alloc(3072ull * 1536);  // merged q_up
  u16* bkvu  = alloc(4096ull * 512);
  u16* bwo   = alloc(2048ull * 2048);
  u16* cqkv  = alloc(4096ull * 2176);  // fused down-proj output
  u16* cq    = alloc(4096ull * 1536);
  u16* qnr   = alloc(4096ull * 3072);
  u16* ckv   = alloc(4096ull * 512);
  u16* kvu   = alloc(4096ull * 4096);
  u16* qp    = alloc(32ull * 2048 * 192);
  u16* kp    = alloc(32ull * 2048 * 192);
  u16* vp    = alloc(32ull * 2048 * 128);
  u16* ao    = alloc(4096ull * 2048);
  if (ws_size < off) return;

  // attn partials alias the cqkv..kvu region (93.4MB), dead after pack_dual:
  // PO = 2 splits x 32 bh x 2048 t x 128 f32 (64MB), ML = 2x32x2048 f32x2 (1MB)
  float* PO = (float*)cqkv;
  float* ML = (float*)((char*)cqkv + 67108864);

  cast_f32_bf16<<<8192, 256, 0, stream>>>(x, x16, 4096 * 2048);

  // down-proj weight transposes (feed gemm1) — own dispatch
  CTSegs S1;
  S1.in[0] = wqd;  S1.out[0] = bqkvd;                  S1.R[0] = 2048; S1.C[0] = 1536; S1.gx[0] = 48;
  S1.in[1] = wkvd; S1.out[1] = bqkvd + 1536ull * 2048; S1.R[1] = 2048; S1.C[1] = 576;  S1.gx[1] = 20;
  S1.start[0] = 0;
  S1.start[1] = 48 * 64;
#pragma unroll
  for (int k = 2; k < 6; k++) { S1.in[k] = wqd; S1.out[k] = bqkvd; S1.R[k] = 32; S1.C[k] = 32; S1.gx[k] = 1; S1.start[k] = 0x7fffffff; }
  castT_multi<<<48 * 64 + 20 * 64, 256, 0, stream>>>(S1);

  // up-proj + wo transposes ride behind gemm1 (independent of it)
  CTSegs S2;
  S2.in[0] = wqun; S2.out[0] = bqu;                  S2.R[0] = 1536; S2.C[0] = 2048; S2.gx[0] = 64;
  S2.in[1] = wqur; S2.out[1] = bqu + 2048ull * 1536; S2.R[1] = 1536; S2.C[1] = 1024; S2.gx[1] = 32;
  S2.in[2] = wkvu; S2.out[2] = bkvu;                 S2.R[2] = 512;  S2.C[2] = 4096; S2.gx[2] = 128;
  S2.in[3] = wwo;  S2.out[3] = bwo;                  S2.R[3] = 2048; S2.C[3] = 2048; S2.gx[3] = 64;
  int gy2[4] = {48, 48, 16, 64};
  int tot2 = 0;
  for (int k = 0; k < 4; k++) { S2.start[k] = tot2; tot2 += S2.gx[k] * gy2[k]; }
  S2.in[4] = wqun; S2.out[4] = bqu; S2.R[4] = 32; S2.C[4] = 32; S2.gx[4] = 1; S2.start[4] = 0x7fffffff;
  S2.in[5] = wqun; S2.out[5] = bqu; S2.R[5] = 32; S2.C[5] = 32; S2.gx[5] = 1; S2.start[5] = 0x7fffffff;
  gemm1_castT<<<544 + tot2, 256, 0, stream>>>(x16, bqkvd, cqkv, S2);

  rmsnorm_dual<<<8192, 256, 0, stream>>>(cqkv, cq, qnw, ckv, kvnw);
  // q_up (K=1536) and kv_up (K=512) fused: long-K z=0 first, short-K backfills
  gemm_bt2<<<dim3(32, 32, 2), 256, 0, stream>>>(cq, bqu, qnr, 3072, 1536, 24,
                                                ckv, bkvu, kvu, 4096, 512, 32);
  pack_dual<<<17408, 256, 0, stream>>>(qnr, qhnw, fcos, fsin, qp,
                                       kvu, cqkv + 1536, khnw, kp, vp);
  attn_kernel<<<1024, 256, 0, stream>>>(qp, kp, vp, PO, ML);
  attn_merge<<<8192, 256, 0, stream>>>(PO, ML, ao);
  gemm_bt<<<dim3(16, 32), 256, 0, stream>>>(ao, bwo, out, 4096, 2048, 2048, 1);
}